// Round 18
// baseline (954.400 us; speedup 1.0000x reference)
//
#include <hip/hip_runtime.h>
#include <hip/hip_bf16.h>
#include <cstdint>

#define DIM   2048
#define HEADS 16
#define HD    128
#define SEQ   2048
#define CLEN  512
#define FFND  8192
#define BATCH 2

using bf16 = __hip_bfloat16;
typedef __attribute__((ext_vector_type(8))) short  short8;
typedef __attribute__((ext_vector_type(4))) short  short4v;
typedef __attribute__((ext_vector_type(4))) float  f32x4;
typedef __attribute__((ext_vector_type(8))) __bf16 bf16x8;

__device__ __forceinline__ short f2bs(float f){ bf16 h = __float2bfloat16(f); return __builtin_bit_cast(short, h); }
__device__ __forceinline__ float bs2f(short s){ return __builtin_bit_cast(float, (uint32_t)((uint16_t)s) << 16); }

__device__ __forceinline__ f32x4 mfma16(short8 a, short8 b, f32x4 c){
  return __builtin_amdgcn_mfma_f32_16x16x32_bf16(
      __builtin_bit_cast(bf16x8, a), __builtin_bit_cast(bf16x8, b), c, 0, 0, 0);
}

__device__ __forceinline__ void gload_lds16(const void* g, const void* l){
  __builtin_amdgcn_global_load_lds(
      (const __attribute__((address_space(1))) void*)(uintptr_t)g,
      (__attribute__((address_space(3))) void*)(uint32_t)(uintptr_t)l, 16, 0, 0);
}

__device__ __forceinline__ float block_sum(float v, float* sbuf, int tid){
  #pragma unroll
  for (int m = 32; m >= 1; m >>= 1) v += __shfl_xor(v, m, 64);
  const int w = tid >> 6;
  if ((tid & 63) == 0) sbuf[w] = v;
  __syncthreads();
  float r = sbuf[0] + sbuf[1] + sbuf[2] + sbuf[3];
  __syncthreads();
  return r;
}

// ---------------- small elementwise kernels ----------------

__global__ void modadd_k(const float* __restrict__ m, const float* __restrict__ e,
                         float* __restrict__ out){
  int i = blockIdx.x * 256 + threadIdx.x;
  out[i] = m[i % (6 * DIM)] + e[i];
}

__global__ void f2b8_k(const float* __restrict__ in, bf16* __restrict__ out){
  int i = blockIdx.x * 256 + threadIdx.x;
  const float4* p = (const float4*)in;
  float4 a = p[2*i], c = p[2*i+1];
  short8 o;
  o[0]=f2bs(a.x); o[1]=f2bs(a.y); o[2]=f2bs(a.z); o[3]=f2bs(a.w);
  o[4]=f2bs(c.x); o[5]=f2bs(c.y); o[6]=f2bs(c.z); o[7]=f2bs(c.w);
  *((short8*)out + i) = o;
}

// bcat[0:3*DIM) = saqb||sakb||savb ; bcat2[0:2*DIM) = cakb||cavb
__global__ void biascat_k(const float* __restrict__ b0, const float* __restrict__ b1,
                          const float* __restrict__ b2, const float* __restrict__ c0,
                          const float* __restrict__ c1, float* __restrict__ bcat,
                          float* __restrict__ bcat2){
  int i = blockIdx.x * 256 + threadIdx.x;
  if (i < 3*DIM){
    const float* src = (i < DIM) ? b0 : (i < 2*DIM) ? b1 : b2;
    bcat[i] = src[i & (DIM-1)];
  } else {
    int j = i - 3*DIM;
    const float* src = (j < DIM) ? c0 : c1;
    bcat2[j] = src[j & (DIM-1)];
  }
}

// transpose + f32->bf16: W[K][N] -> Wt[N][K]; 64x64 tiles, short4 (8B) writes
__global__ __launch_bounds__(256) void transpose_w(const float* __restrict__ W,
                                                   bf16* __restrict__ Wt, int K, int N){
  __shared__ float tile[64][65];
  const int tx = threadIdx.x & 63, ty = threadIdx.x >> 6;
  const size_t k0 = (size_t)blockIdx.y * 64, n0 = (size_t)blockIdx.x * 64;
  #pragma unroll
  for (int i = 0; i < 16; i++)
    tile[ty + i*4][tx] = W[(k0 + ty + i*4) * (size_t)N + n0 + tx];
  __syncthreads();
  const int kx = threadIdx.x & 15;
  const int ny = threadIdx.x >> 4;
  #pragma unroll
  for (int i = 0; i < 4; i++){
    const int n = ny + i*16;
    short4v o;
    #pragma unroll
    for (int j = 0; j < 4; j++) o[j] = f2bs(tile[kx*4 + j][n]);
    *(short4v*)&Wt[(n0 + n) * (size_t)K + k0 + kx*4] = o;
  }
}

// 3 square transposes in one launch (blockIdx.z selects source; dst offset z*K*N)
__global__ __launch_bounds__(256) void transpose_w3(const float* __restrict__ W0,
    const float* __restrict__ W1, const float* __restrict__ W2,
    bf16* __restrict__ Wt, int K, int N){
  __shared__ float tile[64][65];
  const float* W = (blockIdx.z == 0) ? W0 : (blockIdx.z == 1) ? W1 : W2;
  bf16* dst = Wt + (size_t)blockIdx.z * K * N;
  const int tx = threadIdx.x & 63, ty = threadIdx.x >> 6;
  const size_t k0 = (size_t)blockIdx.y * 64, n0 = (size_t)blockIdx.x * 64;
  #pragma unroll
  for (int i = 0; i < 16; i++)
    tile[ty + i*4][tx] = W[(k0 + ty + i*4) * (size_t)N + n0 + tx];
  __syncthreads();
  const int kx = threadIdx.x & 15;
  const int ny = threadIdx.x >> 4;
  #pragma unroll
  for (int i = 0; i < 4; i++){
    const int n = ny + i*16;
    short4v o;
    #pragma unroll
    for (int j = 0; j < 4; j++) o[j] = f2bs(tile[kx*4 + j][n]);
    *(short4v*)&dst[(n0 + n) * (size_t)K + k0 + kx*4] = o;
  }
}

// MODE 1: out = bf16( rms(x)*w1*(1+e1) + e0 )
// MODE 2: out = bf16( rms(x)*w1 )
// MODE 3: t = rms_a(x)*w1*(1+e4)+e3 ; out = bf16( rms_b(t)*w2 )
template<int MODE>
__global__ __launch_bounds__(256) void norm_x(const float* __restrict__ x,
    const float* __restrict__ w1, const float* __restrict__ w2,
    const float* __restrict__ mod, bf16* __restrict__ out, int S)
{
  const int row = blockIdx.x, tid = threadIdx.x;
  const int b = row / S;
  __shared__ float sbuf[4];
  const float* xr = x + (size_t)row * DIM;
  float v[8];
  #pragma unroll
  for (int i = 0; i < 2; i++){
    float4 t = *(const float4*)(xr + i*1024 + tid*4);
    v[i*4+0]=t.x; v[i*4+1]=t.y; v[i*4+2]=t.z; v[i*4+3]=t.w;
  }
  float ss = 0.f;
  #pragma unroll
  for (int j = 0; j < 8; j++) ss += v[j]*v[j];
  ss = block_sum(ss, sbuf, tid);
  const float r = rsqrtf(ss * (1.0f/DIM) + 1e-6f);
  const float* mb = mod + (size_t)b * 6 * DIM;
  float t8[8];
  #pragma unroll
  for (int i = 0; i < 2; i++)
    #pragma unroll
    for (int j = 0; j < 4; j++){
      int n = i*1024 + tid*4 + j;
      float val = v[i*4+j] * r * w1[n];
      if (MODE == 1) val = val * (1.f + mb[DIM + n]) + mb[n];
      if (MODE == 3) val = val * (1.f + mb[4*DIM + n]) + mb[3*DIM + n];
      t8[i*4+j] = val;
    }
  if (MODE == 3){
    float s2 = 0.f;
    #pragma unroll
    for (int j = 0; j < 8; j++) s2 += t8[j]*t8[j];
    s2 = block_sum(s2, sbuf, tid);
    const float r2 = rsqrtf(s2 * (1.0f/DIM) + 1e-6f);
    #pragma unroll
    for (int i = 0; i < 2; i++)
      #pragma unroll
      for (int j = 0; j < 4; j++){
        int n = i*1024 + tid*4 + j;
        t8[i*4+j] = t8[i*4+j] * r2 * w2[n];
      }
  }
  #pragma unroll
  for (int i = 0; i < 2; i++){
    short4v o;
    #pragma unroll
    for (int j = 0; j < 4; j++) o[j] = f2bs(t8[i*4+j]);
    *(short4v*)(out + (size_t)row*DIM + i*1024 + tid*4) = o;
  }
}

// in-place rmsnorm on bf16 rows: rows [0,M) -> xq with wq, rows [M,2M) -> xk with wk
__global__ __launch_bounds__(256) void rmsnorm2_bf16_ip(bf16* __restrict__ xq, const float* __restrict__ wq,
                                                        bf16* __restrict__ xk, const float* __restrict__ wk,
                                                        int M){
  const int row = blockIdx.x, tid = threadIdx.x;
  __shared__ float sbuf[4];
  bf16* xr; const float* w;
  if (row < M){ xr = xq + (size_t)row * DIM; w = wq; }
  else        { xr = xk + (size_t)(row - M) * DIM; w = wk; }
  short8 v = *(const short8*)(xr + tid*8);
  float f[8]; float ss = 0.f;
  #pragma unroll
  for (int j = 0; j < 8; j++){ f[j] = bs2f(v[j]); ss += f[j]*f[j]; }
  ss = block_sum(ss, sbuf, tid);
  const float r = rsqrtf(ss * (1.0f/DIM) + 1e-6f);
  short8 o;
  #pragma unroll
  for (int j = 0; j < 8; j++) o[j] = f2bs(f[j] * r * w[tid*8 + j]);
  *(short8*)(xr + tid*8) = o;
}

// ---------------- GEMM v13: dbuf-2 drain (m97-style) at 3 blocks/CU ----------------
// BM=128, BN=256, BK=32; 512 threads = 8 waves (2M x 4N), per-wave 64x64.
// DOUBLE-buffered LDS (48 KB -> 3 blocks/CU, 24 waves/CU): per m114, cross-
// block implicit overlap beats intra-block counted-vmcnt at lower residency
// (m103: 912 TF for this geometry WITH conflicts; we add 0-conflict swizzle).
// Loop: stage(t+1) into buf^1; ds_read+MFMA from buf; vmcnt(0); barrier.
// Seg-XOR swizzle both sides (verified 0 conflicts).
// EPI 0: outb=bf16  1: Vt layout  2: outf=xin+v*mod[eidx]  3: outf+=v
// EPI 4: gelu->outb  5: QKV split (N=6144)  6: KV split (N=4096)
#define GBUF 24576
template<int EPI>
__global__ __launch_bounds__(512, 2) void gemm_bf16(
    const bf16* __restrict__ A, const bf16* __restrict__ Bt,
    const float* __restrict__ bias, const float* __restrict__ xin,
    const float* __restrict__ mod, float* __restrict__ outf,
    bf16* __restrict__ outb, bf16* __restrict__ out1, bf16* __restrict__ out2,
    int M, int N, int K, int S_tok, int eidx)
{
  __shared__ __align__(16) char lds[2][GBUF];
  const int tid = threadIdx.x;
  const int w = tid >> 6, l = tid & 63;
  const int lrow = l & 15, lhi = l >> 4;
  const int wm = w >> 2, wn = w & 3;
  const size_t m0 = (size_t)blockIdx.y * 128, n0 = (size_t)blockIdx.x * 256;

  f32x4 acc[4][4] = {};

  auto gofs = [&](int sid){ return (size_t)(sid >> 2) * K + (size_t)(((sid & 3) ^ ((sid >> 3) & 3)) * 8); };
  const bf16* gA0 = A  + m0 * K + gofs(tid);
  const bf16* gB0 = Bt + n0 * K + gofs(tid);
  const bf16* gB1 = Bt + n0 * K + gofs(tid + 512);

  auto stage = [&](int kt, char* buf){
    const size_t ko = (size_t)kt * 32;
    gload_lds16(gA0 + ko, buf + tid * 16);
    gload_lds16(gB0 + ko, buf + 8192 + tid * 16);
    gload_lds16(gB1 + ko, buf + 8192 + (tid + 512) * 16);
  };

  const int nt = K >> 5;
  stage(0, lds[0]);
  asm volatile("s_waitcnt vmcnt(0)" ::: "memory");
  __builtin_amdgcn_s_barrier();

  const int sread = (lhi ^ ((lrow >> 1) & 3)) * 16;

  for (int t = 0; t < nt; ++t){
    const char* br = lds[t & 1];
    if (t + 1 < nt) stage(t + 1, lds[(t + 1) & 1]);
    short8 af[4], bf[4];
    #pragma unroll
    for (int mi = 0; mi < 4; mi++)
      af[mi] = *(const short8*)(br + (wm*64 + mi*16 + lrow)*64 + sread);
    #pragma unroll
    for (int ni = 0; ni < 4; ni++)
      bf[ni] = *(const short8*)(br + 8192 + (wn*64 + ni*16 + lrow)*64 + sread);
    __builtin_amdgcn_s_setprio(1);
    #pragma unroll
    for (int mi = 0; mi < 4; mi++)
      #pragma unroll
      for (int ni = 0; ni < 4; ni++)
        acc[mi][ni] = mfma16(af[mi], bf[ni], acc[mi][ni]);
    __builtin_amdgcn_s_setprio(0);
    if (t + 1 < nt) { asm volatile("s_waitcnt vmcnt(0)" ::: "memory"); }
    __builtin_amdgcn_s_barrier();
  }

  #pragma unroll
  for (int mi = 0; mi < 4; mi++)
    #pragma unroll
    for (int ni = 0; ni < 4; ni++)
      #pragma unroll
      for (int r = 0; r < 4; r++){
        const size_t m = m0 + wm*64 + mi*16 + lhi*4 + r;
        const size_t n = n0 + wn*64 + ni*16 + lrow;
        float v = acc[mi][ni][r] + bias[n];
        if constexpr (EPI == 0) {
          outb[m * N + n] = __float2bfloat16(v);
        } else if constexpr (EPI == 1) {
          const size_t b = m / S_tok, s = m % S_tok;
          const size_t h = n >> 7, d = n & 127;
          outb[((b*HEADS + h)*HD + d) * S_tok + s] = __float2bfloat16(v);
        } else if constexpr (EPI == 2) {
          const float ev = mod[(m / S_tok) * 6 * DIM + (size_t)eidx * DIM + n];
          outf[m * N + n] = xin[m * N + n] + v * ev;
        } else if constexpr (EPI == 3) {
          outf[m * N + n] += v;
        } else if constexpr (EPI == 4) {
          float u = 0.7978845608028654f * (v + 0.044715f * v * v * v);
          outb[m * N + n] = __float2bfloat16(0.5f * v * (1.0f + tanhf(u)));
        } else if constexpr (EPI == 5) {   // QKV split (N = 6144)
          const size_t sg = n >> 11, col = n & 2047;
          if (sg == 0)      outb[m * DIM + col] = __float2bfloat16(v);
          else if (sg == 1) out1[m * DIM + col] = __float2bfloat16(v);
          else {
            const size_t b = m / S_tok, s = m % S_tok;
            const size_t h = col >> 7, d = col & 127;
            out2[((b*HEADS + h)*HD + d) * S_tok + s] = __float2bfloat16(v);
          }
        } else {   // EPI 6: KV split (N = 4096)
          const size_t sg = n >> 11, col = n & 2047;
          if (sg == 0) out1[m * DIM + col] = __float2bfloat16(v);
          else {
            const size_t b = m / S_tok, s = m % S_tok;
            const size_t h = col >> 7, d = col & 127;
            out2[((b*HEADS + h)*HD + d) * S_tok + s] = __float2bfloat16(v);
          }
        }
      }
}

// ---------------- flash attention: 32 q-rows/wave, V single-buf LDS, setprio + defer-max ----------------
__global__ __launch_bounds__(256, 2) void attn_fwd(
    const bf16* __restrict__ Q, const bf16* __restrict__ Kp, const bf16* __restrict__ Vt,
    bf16* __restrict__ O, int SQ, int SKV)
{
  const int tid = threadIdx.x, w = tid >> 6, l = tid & 63;
  const int lrow = l & 15, lhi = l >> 4;
  const int nwg = gridDim.x;
  const int p = blockIdx.x;
  const int f = (p & 7) * (nwg >> 3) + (p >> 3);
  const int nqb = SQ >> 7;
  const int xq = f % nqb;
  const int h  = (f / nqb) % HEADS;
  const int b  = f / (nqb * HEADS);
  const int q0 = xq * 128 + w * 32;

  __shared__ __align__(16) char kls[2][16384];
  __shared__ __align__(16) char vls[16384];
  __shared__ __align__(16) bf16 P[4][2][16][72];
  const float scale = 0.08838834764831845f;

  short8 qf[2][4];
  #pragma unroll
  for (int g = 0; g < 2; g++){
    const bf16* qp = Q + ((size_t)(b*SQ + q0 + g*16 + lrow))*DIM + h*HD + lhi*8;
    #pragma unroll
    for (int ds = 0; ds < 4; ds++) qf[g][ds] = *(const short8*)(qp + ds*32);
  }

  const bf16* kg = Kp + (size_t)b*SKV*DIM + h*HD;
  const bf16* vg = Vt + (size_t)(b*HEADS + h)*HD*SKV;

  f32x4 acc[2][8] = {};
  float m_run[2] = {-INFINITY, -INFINITY}, l_run[2] = {0.f, 0.f};
  const int nt = SKV >> 6;

  auto stage_k = [&](int buf, int kv0){
    char* kd = &kls[buf][0];
    #pragma unroll
    for (int i = 0; i < 4; i++){
      int sid = i*256 + tid;
      int row = sid >> 4, sg = sid & 15;
      int gsg = sg ^ (row & 7);
      gload_lds16(kg + (size_t)(kv0 + row)*DIM + gsg*8, kd + sid*16);
    }
  };
  auto stage_v = [&](int kv0){
    #pragma unroll
    for (int i = 0; i < 4; i++){
      int sid = i*256 + tid;
      int d = sid >> 3, sg = sid & 7;
      int gsg = sg ^ (d & 7);
      gload_lds16(vg + (size_t)d*SKV + kv0 + gsg*8, &vls[0] + sid*16);
    }
  };

  stage_k(0, 0);
  stage_v(0);
  asm volatile("s_waitcnt vmcnt(0)" ::: "memory");
  __builtin_amdgcn_s_barrier();

  for (int t = 0; t < nt; ++t){
    if (t > 0)      stage_v(t * 64);
    if (t + 1 < nt) stage_k((t + 1) & 1, (t + 1) * 64);
    const char* kb = &kls[t & 1][0];

    f32x4 st[2][4] = {};
    __builtin_amdgcn_s_setprio(1);
    #pragma unroll
    for (int kvf = 0; kvf < 4; kvf++){
      const int row = kvf*16 + lrow;
      const int rx = row & 7;
      #pragma unroll
      for (int ds = 0; ds < 4; ds++){
        const int seg = (ds*4 + lhi) ^ rx;
        short8 kf = *(const short8*)(kb + row*256 + seg*16);
        st[0][kvf] = mfma16(kf, qf[0][ds], st[0][kvf]);
        st[1][kvf] = mfma16(kf, qf[1][ds], st[1][kvf]);
      }
    }
    __builtin_amdgcn_s_setprio(0);

    #pragma unroll
    for (int g = 0; g < 2; g++){
      float sv[16]; float smax = -INFINITY;
      #pragma unroll
      for (int kvf = 0; kvf < 4; kvf++)
        #pragma unroll
        for (int r = 0; r < 4; r++){
          float xv = st[g][kvf][r] * scale;
          sv[kvf*4+r] = xv; smax = fmaxf(smax, xv);
        }
      smax = fmaxf(smax, __shfl_xor(smax, 16, 64));
      smax = fmaxf(smax, __shfl_xor(smax, 32, 64));
      const bool nore = __all(smax <= m_run[g] + 8.0f);
      const float mnew = nore ? m_run[g] : fmaxf(m_run[g], smax);
      float psum = 0.f;
      #pragma unroll
      for (int i = 0; i < 16; i++){ float pe = __expf(sv[i] - mnew); sv[i] = pe; psum += pe; }
      psum += __shfl_xor(psum, 16, 64); psum += __shfl_xor(psum, 32, 64);
      #pragma unroll
      for (int kvf = 0; kvf < 4; kvf++){
        short4v o;
        #pragma unroll
        for (int r = 0; r < 4; r++) o[r] = f2bs(sv[kvf*4+r]);
        *(short4v*)&P[w][g][lrow][kvf*16 + lhi*4] = o;
      }
      if (nore){
        l_run[g] += psum;
      } else {
        const float corr = __expf(m_run[g] - mnew);
        l_run[g] = l_run[g] * corr + psum;
        m_run[g] = mnew;
        float cr[4];
        #pragma unroll
        for (int r = 0; r < 4; r++) cr[r] = __shfl(corr, lhi*4 + r, 64);
        #pragma unroll
        for (int df = 0; df < 8; df++){
          acc[g][df][0] *= cr[0]; acc[g][df][1] *= cr[1];
          acc[g][df][2] *= cr[2]; acc[g][df][3] *= cr[3];
        }
      }
    }

    if (t + 1 < nt) { asm volatile("s_waitcnt vmcnt(4)" ::: "memory"); }
    else            { asm volatile("s_waitcnt vmcnt(0)" ::: "memory"); }
    __builtin_amdgcn_s_barrier();
    asm volatile("s_waitcnt lgkmcnt(0)" ::: "memory");
    __builtin_amdgcn_sched_barrier(0);

    short8 pf[2][2];
    #pragma unroll
    for (int g = 0; g < 2; g++){
      pf[g][0] = *(const short8*)&P[w][g][lrow][lhi*8];
      pf[g][1] = *(const short8*)&P[w][g][lrow][32 + lhi*8];
    }
    __builtin_amdgcn_s_setprio(1);
    #pragma unroll
    for (int df = 0; df < 8; df++){
      const int d = df*16 + lrow;
      const int dx = d & 7;
      short8 vf0 = *(const short8*)(&vls[0] + d*128 + ((lhi)     ^ dx)*16);
      short8 vf1 = *(const short8*)(&vls[0] + d*128 + ((lhi + 4) ^ dx)*16);
      acc[0][df] = mfma16(pf[0][0], vf0, acc[0][df]);
      acc[0][df] = mfma16(pf[0][1], vf1, acc[0][df]);
      acc[1][df] = mfma16(pf[1][0], vf0, acc[1][df]);
      acc[1][df] = mfma16(pf[1][1], vf1, acc[1][df]);
    }
    __builtin_amdgcn_s_setprio(0);
    if (t + 1 < nt) { asm volatile("s_waitcnt vmcnt(0)" ::: "memory"); }
    __builtin_amdgcn_s_barrier();
  }

  #pragma unroll
  for (int g = 0; g < 2; g++){
    const float linv = 1.0f / l_run[g];
    float li[4];
    #pragma unroll
    for (int r = 0; r < 4; r++) li[r] = __shfl(linv, lhi*4 + r, 64);
    #pragma unroll
    for (int df = 0; df < 8; df++)
      #pragma unroll
      for (int r = 0; r < 4; r++){
        const size_t q = q0 + g*16 + lhi*4 + r;
        O[((size_t)(b*SQ + q))*DIM + h*HD + df*16 + lrow] = __float2bfloat16(acc[g][df][r] * li[r]);
      }
  }
}

// ---------------- host ----------------

extern "C" void kernel_launch(void* const* d_in, const int* in_sizes, int n_in,
                              void* d_out, int out_size, void* d_ws, size_t ws_size,
                              hipStream_t stream)
{
  const float* x    = (const float*)d_in[0];
  const float* e    = (const float*)d_in[1];
  const float* ctx  = (const float*)d_in[2];
  const float* modw = (const float*)d_in[3];
  const float* n1w  = (const float*)d_in[4];
  const float* n2w  = (const float*)d_in[5];
  const float* n3w  = (const float*)d_in[6];
  const float* nqw  = (const float*)d_in[7];
  const float* nkw  = (const float*)d_in[8];
  const float* fnw  = (const float*)d_in[9];
  const float* saqw = (const float*)d_in[10]; const float* saqb = (const float*)d_in[11];
  const float* sakw = (const float*)d_in[12]; const float* sakb = (const float*)d_in[13];
  const float* savw = (const float*)d_in[14]; const float* savb = (const float*)d_in[15];
  const float* saow = (const float*)d_in[16]; const float* saob = (const float*)d_in[17];
  const float* caqw = (const float*)d_in[18]; const float* caqb = (const float*)d_in[19];
  const float* cakw = (const float*)d_in[20]; const float* cakb = (const float*)d_in[21];
  const float* cavw = (const float*)d_in[22]; const float* cavb = (const float*)d_in[23];
  const float* caow = (const float*)d_in[24]; const float* caob = (const float*)d_in[25];
  const float* fw1  = (const float*)d_in[26]; const float* fb1  = (const float*)d_in[27];
  const float* fw2  = (const float*)d_in[28]; const float* fb2  = (const float*)d_in[29];
  float* out = (float*)d_out;
  (void)in_sizes; (void)n_in; (void)out_size; (void)ws_size;

  char* ws = (char*)d_ws;
  size_t off = 0;
  auto alloc = [&](size_t bytes) -> void* {
    void* p = ws + off; off = (off + bytes + 255) & ~(size_t)255; return p;
  };
  bf16*  wt   = (bf16*)alloc((size_t)FFND * DIM * 2);
  float* mod  = (float*)alloc((size_t)BATCH * 6 * DIM * 4);
  float* bcat = (float*)alloc((size_t)3 * DIM * 4);
  float* bcat2= (float*)alloc((size_t)2 * DIM * 4);
  bf16*  ctxb = (bf16*)alloc((size_t)BATCH * CLEN * DIM * 2);
  bf16*  hbuf = (bf16*)alloc((size_t)BATCH * SEQ * DIM * 2);
  bf16*  qbuf = (bf16*)alloc((size_t)BATCH * SEQ * DIM * 2);
  bf16*  kbuf = (bf16*)alloc((size_t)BATCH * SEQ * DIM * 2);
  bf16*  vtb  = (bf16*)alloc((size_t)BATCH * SEQ * DIM * 2);
  bf16*  aout = (bf16*)alloc((size_t)BATCH * SEQ * DIM * 2);
  float* xcur = (float*)alloc((size_t)BATCH * SEQ * DIM * 4);
  bf16*  hf   = (bf16*)alloc((size_t)BATCH * SEQ * FFND * 2);

  const int M = BATCH * SEQ;     // 4096
  const int Mc = BATCH * CLEN;   // 1024

  modadd_k<<<dim3(96), dim3(256), 0, stream>>>(modw, e, mod);
  f2b8_k<<<dim3(1024), dim3(256), 0, stream>>>(ctx, ctxb);
  biascat_k<<<dim3(40), dim3(256), 0, stream>>>(saqb, sakb, savb, cakb, cavb, bcat, bcat2);

  // --- self attention: fused QKV (N=6144) ---
  norm_x<1><<<dim3(M), dim3(256), 0, stream>>>(x, n1w, nullptr, mod, hbuf, SEQ);

  transpose_w3<<<dim3(DIM/64, DIM/64, 3), dim3(256), 0, stream>>>(saqw, sakw, savw, wt, DIM, DIM);
  gemm_bf16<5><<<dim3(3*DIM/256, M/128), dim3(512), 0, stream>>>(hbuf, wt, bcat, nullptr, nullptr, nullptr, qbuf, kbuf, vtb, M, 3*DIM, DIM, SEQ, 0);
  rmsnorm2_bf16_ip<<<dim3(2*M), dim3(256), 0, stream>>>(qbuf, nqw, kbuf, nkw, M);

  attn_fwd<<<dim3((SEQ/128)*HEADS*BATCH), dim3(256), 0, stream>>>(qbuf, kbuf, vtb, aout, SEQ, SEQ);

  transpose_w<<<dim3(DIM/64, DIM/64), dim3(256), 0, stream>>>(saow, wt, DIM, DIM);
  gemm_bf16<2><<<dim3(DIM/256, M/128), dim3(512), 0, stream>>>(aout, wt, saob, x, mod, xcur, nullptr, nullptr, nullptr, M, DIM, DIM, SEQ, 2);

  // --- cross attention: q gemm + fused KV gemm (N=4096) ---
  norm_x<2><<<dim3(M), dim3(256), 0, stream>>>(xcur, n2w, nullptr, mod, hbuf, SEQ);

  transpose_w3<<<dim3(DIM/64, DIM/64, 3), dim3(256), 0, stream>>>(caqw, cakw, cavw, wt, DIM, DIM);
  gemm_bf16<0><<<dim3(DIM/256, M/128), dim3(512), 0, stream>>>(hbuf, wt, caqb, nullptr, nullptr, nullptr, qbuf, nullptr, nullptr, M, DIM, DIM, SEQ, 0);
  gemm_bf16<6><<<dim3(2*DIM/256, Mc/128), dim3(512), 0, stream>>>(ctxb, wt + (size_t)DIM*DIM, bcat2, nullptr, nullptr, nullptr, nullptr, kbuf, vtb, Mc, 2*DIM, DIM, CLEN, 0);

  attn_fwd<<<dim3((SEQ/128)*HEADS*BATCH), dim3(256), 0, stream>>>(qbuf, kbuf, vtb, aout, SEQ, CLEN);

  transpose_w<<<dim3(DIM/64, DIM/64), dim3(256), 0, stream>>>(caow, wt, DIM, DIM);
  gemm_bf16<3><<<dim3(DIM/256, M/128), dim3(512), 0, stream>>>(aout, wt, caob, nullptr, nullptr, xcur, nullptr, nullptr, nullptr, M, DIM, DIM, SEQ, 0);

  // --- FFN ---
  norm_x<3><<<dim3(M), dim3(256), 0, stream>>>(xcur, n3w, fnw, mod, hbuf, SEQ);

  transpose_w<<<dim3(FFND/64, DIM/64), dim3(256), 0, stream>>>(fw1, wt, DIM, FFND);
  gemm_bf16<4><<<dim3(FFND/256, M/128), dim3(512), 0, stream>>>(hbuf, wt, fb1, nullptr, nullptr, nullptr, hf, nullptr, nullptr, M, FFND, DIM, SEQ, 0);

  transpose_w<<<dim3(DIM/64, FFND/64), dim3(256), 0, stream>>>(fw2, wt, FFND, DIM);
  gemm_bf16<2><<<dim3(DIM/256, M/128), dim3(512), 0, stream>>>(hf, wt, fb2, xcur, mod, out, nullptr, nullptr, nullptr, M, DIM, FFND, SEQ, 5);
}

// Round 19
// 887.812 us; speedup vs baseline: 1.0750x; 1.0750x over previous
//
#include <hip/hip_runtime.h>
#include <hip/hip_bf16.h>
#include <cstdint>

#define DIM   2048
#define HEADS 16
#define HD    128
#define SEQ   2048
#define CLEN  512
#define FFND  8192
#define BATCH 2

using bf16 = __hip_bfloat16;
typedef __attribute__((ext_vector_type(8))) short  short8;
typedef __attribute__((ext_vector_type(4))) short  short4v;
typedef __attribute__((ext_vector_type(4))) float  f32x4;
typedef __attribute__((ext_vector_type(8))) __bf16 bf16x8;

__device__ __forceinline__ short f2bs(float f){ bf16 h = __float2bfloat16(f); return __builtin_bit_cast(short, h); }
__device__ __forceinline__ float bs2f(short s){ return __builtin_bit_cast(float, (uint32_t)((uint16_t)s) << 16); }

__device__ __forceinline__ f32x4 mfma16(short8 a, short8 b, f32x4 c){
  return __builtin_amdgcn_mfma_f32_16x16x32_bf16(
      __builtin_bit_cast(bf16x8, a), __builtin_bit_cast(bf16x8, b), c, 0, 0, 0);
}

__device__ __forceinline__ void gload_lds16(const void* g, const void* l){
  __builtin_amdgcn_global_load_lds(
      (const __attribute__((address_space(1))) void*)(uintptr_t)g,
      (__attribute__((address_space(3))) void*)(uint32_t)(uintptr_t)l, 16, 0, 0);
}

__device__ __forceinline__ float block_sum(float v, float* sbuf, int tid){
  #pragma unroll
  for (int m = 32; m >= 1; m >>= 1) v += __shfl_xor(v, m, 64);
  const int w = tid >> 6;
  if ((tid & 63) == 0) sbuf[w] = v;
  __syncthreads();
  float r = sbuf[0] + sbuf[1] + sbuf[2] + sbuf[3];
  __syncthreads();
  return r;
}

// ---------------- small elementwise kernels ----------------

__global__ void modadd_k(const float* __restrict__ m, const float* __restrict__ e,
                         float* __restrict__ out){
  int i = blockIdx.x * 256 + threadIdx.x;
  out[i] = m[i % (6 * DIM)] + e[i];
}

__global__ void f2b8_k(const float* __restrict__ in, bf16* __restrict__ out){
  int i = blockIdx.x * 256 + threadIdx.x;
  const float4* p = (const float4*)in;
  float4 a = p[2*i], c = p[2*i+1];
  short8 o;
  o[0]=f2bs(a.x); o[1]=f2bs(a.y); o[2]=f2bs(a.z); o[3]=f2bs(a.w);
  o[4]=f2bs(c.x); o[5]=f2bs(c.y); o[6]=f2bs(c.z); o[7]=f2bs(c.w);
  *((short8*)out + i) = o;
}

// bcat[0:3*DIM) = saqb||sakb||savb ; bcat2[0:2*DIM) = cakb||cavb
__global__ void biascat_k(const float* __restrict__ b0, const float* __restrict__ b1,
                          const float* __restrict__ b2, const float* __restrict__ c0,
                          const float* __restrict__ c1, float* __restrict__ bcat,
                          float* __restrict__ bcat2){
  int i = blockIdx.x * 256 + threadIdx.x;
  if (i < 3*DIM){
    const float* src = (i < DIM) ? b0 : (i < 2*DIM) ? b1 : b2;
    bcat[i] = src[i & (DIM-1)];
  } else {
    int j = i - 3*DIM;
    const float* src = (j < DIM) ? c0 : c1;
    bcat2[j] = src[j & (DIM-1)];
  }
}

// transpose + f32->bf16: W[K][N] -> Wt[N][K]; 64x64 tiles, short4 (8B) writes
__global__ __launch_bounds__(256) void transpose_w(const float* __restrict__ W,
                                                   bf16* __restrict__ Wt, int K, int N){
  __shared__ float tile[64][65];
  const int tx = threadIdx.x & 63, ty = threadIdx.x >> 6;     // ty 0..3
  const size_t k0 = (size_t)blockIdx.y * 64, n0 = (size_t)blockIdx.x * 64;
  #pragma unroll
  for (int i = 0; i < 16; i++)
    tile[ty + i*4][tx] = W[(k0 + ty + i*4) * (size_t)N + n0 + tx];
  __syncthreads();
  const int kx = threadIdx.x & 15;          // k-quad (4 k each)
  const int ny = threadIdx.x >> 4;          // 0..15
  #pragma unroll
  for (int i = 0; i < 4; i++){
    const int n = ny + i*16;
    short4v o;
    #pragma unroll
    for (int j = 0; j < 4; j++) o[j] = f2bs(tile[kx*4 + j][n]);
    *(short4v*)&Wt[(n0 + n) * (size_t)K + k0 + kx*4] = o;
  }
}

// 3 square transposes in one launch (blockIdx.z selects source; dst offset z*K*N)
__global__ __launch_bounds__(256) void transpose_w3(const float* __restrict__ W0,
    const float* __restrict__ W1, const float* __restrict__ W2,
    bf16* __restrict__ Wt, int K, int N){
  __shared__ float tile[64][65];
  const float* W = (blockIdx.z == 0) ? W0 : (blockIdx.z == 1) ? W1 : W2;
  bf16* dst = Wt + (size_t)blockIdx.z * K * N;
  const int tx = threadIdx.x & 63, ty = threadIdx.x >> 6;
  const size_t k0 = (size_t)blockIdx.y * 64, n0 = (size_t)blockIdx.x * 64;
  #pragma unroll
  for (int i = 0; i < 16; i++)
    tile[ty + i*4][tx] = W[(k0 + ty + i*4) * (size_t)N + n0 + tx];
  __syncthreads();
  const int kx = threadIdx.x & 15;
  const int ny = threadIdx.x >> 4;
  #pragma unroll
  for (int i = 0; i < 4; i++){
    const int n = ny + i*16;
    short4v o;
    #pragma unroll
    for (int j = 0; j < 4; j++) o[j] = f2bs(tile[kx*4 + j][n]);
    *(short4v*)&dst[(n0 + n) * (size_t)K + k0 + kx*4] = o;
  }
}

// MODE 1: out = bf16( rms(x)*w1*(1+e1) + e0 )
// MODE 2: out = bf16( rms(x)*w1 )
// MODE 3: t = rms_a(x)*w1*(1+e4)+e3 ; out = bf16( rms_b(t)*w2 )
template<int MODE>
__global__ __launch_bounds__(256) void norm_x(const float* __restrict__ x,
    const float* __restrict__ w1, const float* __restrict__ w2,
    const float* __restrict__ mod, bf16* __restrict__ out, int S)
{
  const int row = blockIdx.x, tid = threadIdx.x;
  const int b = row / S;
  __shared__ float sbuf[4];
  const float* xr = x + (size_t)row * DIM;
  float v[8];
  #pragma unroll
  for (int i = 0; i < 2; i++){
    float4 t = *(const float4*)(xr + i*1024 + tid*4);
    v[i*4+0]=t.x; v[i*4+1]=t.y; v[i*4+2]=t.z; v[i*4+3]=t.w;
  }
  float ss = 0.f;
  #pragma unroll
  for (int j = 0; j < 8; j++) ss += v[j]*v[j];
  ss = block_sum(ss, sbuf, tid);
  const float r = rsqrtf(ss * (1.0f/DIM) + 1e-6f);
  const float* mb = mod + (size_t)b * 6 * DIM;
  float t8[8];
  #pragma unroll
  for (int i = 0; i < 2; i++)
    #pragma unroll
    for (int j = 0; j < 4; j++){
      int n = i*1024 + tid*4 + j;
      float val = v[i*4+j] * r * w1[n];
      if (MODE == 1) val = val * (1.f + mb[DIM + n]) + mb[n];
      if (MODE == 3) val = val * (1.f + mb[4*DIM + n]) + mb[3*DIM + n];
      t8[i*4+j] = val;
    }
  if (MODE == 3){
    float s2 = 0.f;
    #pragma unroll
    for (int j = 0; j < 8; j++) s2 += t8[j]*t8[j];
    s2 = block_sum(s2, sbuf, tid);
    const float r2 = rsqrtf(s2 * (1.0f/DIM) + 1e-6f);
    #pragma unroll
    for (int i = 0; i < 2; i++)
      #pragma unroll
      for (int j = 0; j < 4; j++){
        int n = i*1024 + tid*4 + j;
        t8[i*4+j] = t8[i*4+j] * r2 * w2[n];
      }
  }
  #pragma unroll
  for (int i = 0; i < 2; i++){
    short4v o;
    #pragma unroll
    for (int j = 0; j < 4; j++) o[j] = f2bs(t8[i*4+j]);
    *(short4v*)(out + (size_t)row*DIM + i*1024 + tid*4) = o;
  }
}

// in-place rmsnorm on bf16 rows: rows [0,M) -> xq with wq, rows [M,2M) -> xk with wk
__global__ __launch_bounds__(256) void rmsnorm2_bf16_ip(bf16* __restrict__ xq, const float* __restrict__ wq,
                                                        bf16* __restrict__ xk, const float* __restrict__ wk,
                                                        int M){
  const int row = blockIdx.x, tid = threadIdx.x;
  __shared__ float sbuf[4];
  bf16* xr; const float* w;
  if (row < M){ xr = xq + (size_t)row * DIM; w = wq; }
  else        { xr = xk + (size_t)(row - M) * DIM; w = wk; }
  short8 v = *(const short8*)(xr + tid*8);
  float f[8]; float ss = 0.f;
  #pragma unroll
  for (int j = 0; j < 8; j++){ f[j] = bs2f(v[j]); ss += f[j]*f[j]; }
  ss = block_sum(ss, sbuf, tid);
  const float r = rsqrtf(ss * (1.0f/DIM) + 1e-6f);
  short8 o;
  #pragma unroll
  for (int j = 0; j < 8; j++) o[j] = f2bs(f[j] * r * w[tid*8 + j]);
  *(short8*)(xr + tid*8) = o;
}

// ---------------- GEMM (r6/r17 champion): BM=128, BN=256, BK=32 ----------------
// 512 threads = 8 waves (2M x 4N), per-wave 64x64. Triple-buffered LDS,
// counted vmcnt(3) (tile t+2 in flight; never drain in steady state),
// seg-XOR swizzle both sides (0 bank conflicts), setprio around MFMA.
// EPI 0: outb=bf16  1: Vt layout  2: outf=xin+v*mod[eidx]  3: outf+=v
// EPI 4: gelu->outb  5: QKV split (N=6144)  6: KV split (N=4096)
#define GBUF 24576
template<int EPI>
__global__ __launch_bounds__(512, 2) void gemm_bf16(
    const bf16* __restrict__ A, const bf16* __restrict__ Bt,
    const float* __restrict__ bias, const float* __restrict__ xin,
    const float* __restrict__ mod, float* __restrict__ outf,
    bf16* __restrict__ outb, bf16* __restrict__ out1, bf16* __restrict__ out2,
    int M, int N, int K, int S_tok, int eidx)
{
  __shared__ __align__(16) char lds[3][GBUF];
  const int tid = threadIdx.x;
  const int w = tid >> 6, l = tid & 63;
  const int lrow = l & 15, lhi = l >> 4;
  const int wm = w >> 2, wn = w & 3;
  const size_t m0 = (size_t)blockIdx.y * 128, n0 = (size_t)blockIdx.x * 256;

  f32x4 acc[4][4] = {};

  auto gofs = [&](int sid){ return (size_t)(sid >> 2) * K + (size_t)(((sid & 3) ^ ((sid >> 3) & 3)) * 8); };
  const bf16* gA0 = A  + m0 * K + gofs(tid);
  const bf16* gB0 = Bt + n0 * K + gofs(tid);
  const bf16* gB1 = Bt + n0 * K + gofs(tid + 512);

  auto stage = [&](int kt, char* buf){
    const size_t ko = (size_t)kt * 32;
    gload_lds16(gA0 + ko, buf + tid * 16);
    gload_lds16(gB0 + ko, buf + 8192 + tid * 16);
    gload_lds16(gB1 + ko, buf + 8192 + (tid + 512) * 16);
  };

  const int nt = K >> 5;
  stage(0, lds[0]);
  stage(1, lds[1]);
  asm volatile("s_waitcnt vmcnt(3)" ::: "memory");
  __builtin_amdgcn_s_barrier();
  __builtin_amdgcn_sched_barrier(0);

  const int sread = (lhi ^ ((lrow >> 1) & 3)) * 16;

  int bi = 0;
  for (int t = 0; t < nt; ++t){
    const char* br = lds[bi];
    const bool st = (t + 2 < nt);
    if (st){
      int wi = bi + 2; if (wi >= 3) wi -= 3;
      stage(t + 2, lds[wi]);
    }
    short8 af[4], bf[4];
    #pragma unroll
    for (int mi = 0; mi < 4; mi++)
      af[mi] = *(const short8*)(br + (wm*64 + mi*16 + lrow)*64 + sread);
    #pragma unroll
    for (int ni = 0; ni < 4; ni++)
      bf[ni] = *(const short8*)(br + 8192 + (wn*64 + ni*16 + lrow)*64 + sread);
    __builtin_amdgcn_s_setprio(1);
    #pragma unroll
    for (int mi = 0; mi < 4; mi++)
      #pragma unroll
      for (int ni = 0; ni < 4; ni++)
        acc[mi][ni] = mfma16(af[mi], bf[ni], acc[mi][ni]);
    __builtin_amdgcn_s_setprio(0);
    if (st)               { asm volatile("s_waitcnt vmcnt(3)" ::: "memory"); }
    else if (t + 1 < nt)  { asm volatile("s_waitcnt vmcnt(0)" ::: "memory"); }
    __builtin_amdgcn_s_barrier();
    __builtin_amdgcn_sched_barrier(0);
    bi = (bi + 1 == 3) ? 0 : bi + 1;
  }

  #pragma unroll
  for (int mi = 0; mi < 4; mi++)
    #pragma unroll
    for (int ni = 0; ni < 4; ni++)
      #pragma unroll
      for (int r = 0; r < 4; r++){
        const size_t m = m0 + wm*64 + mi*16 + lhi*4 + r;
        const size_t n = n0 + wn*64 + ni*16 + lrow;
        float v = acc[mi][ni][r] + bias[n];
        if constexpr (EPI == 0) {
          outb[m * N + n] = __float2bfloat16(v);
        } else if constexpr (EPI == 1) {
          const size_t b = m / S_tok, s = m % S_tok;
          const size_t h = n >> 7, d = n & 127;
          outb[((b*HEADS + h)*HD + d) * S_tok + s] = __float2bfloat16(v);
        } else if constexpr (EPI == 2) {
          const float ev = mod[(m / S_tok) * 6 * DIM + (size_t)eidx * DIM + n];
          outf[m * N + n] = xin[m * N + n] + v * ev;
        } else if constexpr (EPI == 3) {
          outf[m * N + n] += v;
        } else if constexpr (EPI == 4) {
          float u = 0.7978845608028654f * (v + 0.044715f * v * v * v);
          outb[m * N + n] = __float2bfloat16(0.5f * v * (1.0f + tanhf(u)));
        } else if constexpr (EPI == 5) {   // QKV split (N = 6144)
          const size_t sg = n >> 11, col = n & 2047;
          if (sg == 0)      outb[m * DIM + col] = __float2bfloat16(v);
          else if (sg == 1) out1[m * DIM + col] = __float2bfloat16(v);
          else {
            const size_t b = m / S_tok, s = m % S_tok;
            const size_t h = col >> 7, d = col & 127;
            out2[((b*HEADS + h)*HD + d) * S_tok + s] = __float2bfloat16(v);
          }
        } else {   // EPI 6: KV split (N = 4096)
          const size_t sg = n >> 11, col = n & 2047;
          if (sg == 0) out1[m * DIM + col] = __float2bfloat16(v);
          else {
            const size_t b = m / S_tok, s = m % S_tok;
            const size_t h = col >> 7, d = col & 127;
            out2[((b*HEADS + h)*HD + d) * S_tok + s] = __float2bfloat16(v);
          }
        }
      }
}

// ---------------- flash attention: 32 q-rows/wave, V single-buf LDS, setprio + defer-max ----------------
__global__ __launch_bounds__(256, 2) void attn_fwd(
    const bf16* __restrict__ Q, const bf16* __restrict__ Kp, const bf16* __restrict__ Vt,
    bf16* __restrict__ O, int SQ, int SKV)
{
  const int tid = threadIdx.x, w = tid >> 6, l = tid & 63;
  const int lrow = l & 15, lhi = l >> 4;
  const int nwg = gridDim.x;
  const int p = blockIdx.x;
  const int f = (p & 7) * (nwg >> 3) + (p >> 3);
  const int nqb = SQ >> 7;
  const int xq = f % nqb;
  const int h  = (f / nqb) % HEADS;
  const int b  = f / (nqb * HEADS);
  const int q0 = xq * 128 + w * 32;

  __shared__ __align__(16) char kls[2][16384];
  __shared__ __align__(16) char vls[16384];
  __shared__ __align__(16) bf16 P[4][2][16][72];
  const float scale = 0.08838834764831845f;

  short8 qf[2][4];
  #pragma unroll
  for (int g = 0; g < 2; g++){
    const bf16* qp = Q + ((size_t)(b*SQ + q0 + g*16 + lrow))*DIM + h*HD + lhi*8;
    #pragma unroll
    for (int ds = 0; ds < 4; ds++) qf[g][ds] = *(const short8*)(qp + ds*32);
  }

  const bf16* kg = Kp + (size_t)b*SKV*DIM + h*HD;
  const bf16* vg = Vt + (size_t)(b*HEADS + h)*HD*SKV;

  f32x4 acc[2][8] = {};
  float m_run[2] = {-INFINITY, -INFINITY}, l_run[2] = {0.f, 0.f};
  const int nt = SKV >> 6;

  auto stage_k = [&](int buf, int kv0){
    char* kd = &kls[buf][0];
    #pragma unroll
    for (int i = 0; i < 4; i++){
      int sid = i*256 + tid;
      int row = sid >> 4, sg = sid & 15;
      int gsg = sg ^ (row & 7);
      gload_lds16(kg + (size_t)(kv0 + row)*DIM + gsg*8, kd + sid*16);
    }
  };
  auto stage_v = [&](int kv0){
    #pragma unroll
    for (int i = 0; i < 4; i++){
      int sid = i*256 + tid;
      int d = sid >> 3, sg = sid & 7;
      int gsg = sg ^ (d & 7);
      gload_lds16(vg + (size_t)d*SKV + kv0 + gsg*8, &vls[0] + sid*16);
    }
  };

  stage_k(0, 0);
  stage_v(0);
  asm volatile("s_waitcnt vmcnt(0)" ::: "memory");
  __builtin_amdgcn_s_barrier();

  for (int t = 0; t < nt; ++t){
    if (t > 0)      stage_v(t * 64);
    if (t + 1 < nt) stage_k((t + 1) & 1, (t + 1) * 64);
    const char* kb = &kls[t & 1][0];

    f32x4 st[2][4] = {};
    __builtin_amdgcn_s_setprio(1);
    #pragma unroll
    for (int kvf = 0; kvf < 4; kvf++){
      const int row = kvf*16 + lrow;
      const int rx = row & 7;
      #pragma unroll
      for (int ds = 0; ds < 4; ds++){
        const int seg = (ds*4 + lhi) ^ rx;
        short8 kf = *(const short8*)(kb + row*256 + seg*16);
        st[0][kvf] = mfma16(kf, qf[0][ds], st[0][kvf]);
        st[1][kvf] = mfma16(kf, qf[1][ds], st[1][kvf]);
      }
    }
    __builtin_amdgcn_s_setprio(0);

    #pragma unroll
    for (int g = 0; g < 2; g++){
      float sv[16]; float smax = -INFINITY;
      #pragma unroll
      for (int kvf = 0; kvf < 4; kvf++)
        #pragma unroll
        for (int r = 0; r < 4; r++){
          float xv = st[g][kvf][r] * scale;
          sv[kvf*4+r] = xv; smax = fmaxf(smax, xv);
        }
      smax = fmaxf(smax, __shfl_xor(smax, 16, 64));
      smax = fmaxf(smax, __shfl_xor(smax, 32, 64));
      const bool nore = __all(smax <= m_run[g] + 8.0f);
      const float mnew = nore ? m_run[g] : fmaxf(m_run[g], smax);
      float psum = 0.f;
      #pragma unroll
      for (int i = 0; i < 16; i++){ float pe = __expf(sv[i] - mnew); sv[i] = pe; psum += pe; }
      psum += __shfl_xor(psum, 16, 64); psum += __shfl_xor(psum, 32, 64);
      #pragma unroll
      for (int kvf = 0; kvf < 4; kvf++){
        short4v o;
        #pragma unroll
        for (int r = 0; r < 4; r++) o[r] = f2bs(sv[kvf*4+r]);
        *(short4v*)&P[w][g][lrow][kvf*16 + lhi*4] = o;
      }
      if (nore){
        l_run[g] += psum;
      } else {
        const float corr = __expf(m_run[g] - mnew);
        l_run[g] = l_run[g] * corr + psum;
        m_run[g] = mnew;
        float cr[4];
        #pragma unroll
        for (int r = 0; r < 4; r++) cr[r] = __shfl(corr, lhi*4 + r, 64);
        #pragma unroll
        for (int df = 0; df < 8; df++){
          acc[g][df][0] *= cr[0]; acc[g][df][1] *= cr[1];
          acc[g][df][2] *= cr[2]; acc[g][df][3] *= cr[3];
        }
      }
    }

    if (t + 1 < nt) { asm volatile("s_waitcnt vmcnt(4)" ::: "memory"); }
    else            { asm volatile("s_waitcnt vmcnt(0)" ::: "memory"); }
    __builtin_amdgcn_s_barrier();
    asm volatile("s_waitcnt lgkmcnt(0)" ::: "memory");
    __builtin_amdgcn_sched_barrier(0);

    short8 pf[2][2];
    #pragma unroll
    for (int g = 0; g < 2; g++){
      pf[g][0] = *(const short8*)&P[w][g][lrow][lhi*8];
      pf[g][1] = *(const short8*)&P[w][g][lrow][32 + lhi*8];
    }
    __builtin_amdgcn_s_setprio(1);
    #pragma unroll
    for (int df = 0; df < 8; df++){
      const int d = df*16 + lrow;
      const int dx = d & 7;
      short8 vf0 = *(const short8*)(&vls[0] + d*128 + ((lhi)     ^ dx)*16);
      short8 vf1 = *(const short8*)(&vls[0] + d*128 + ((lhi + 4) ^ dx)*16);
      acc[0][df] = mfma16(pf[0][0], vf0, acc[0][df]);
      acc[0][df] = mfma16(pf[0][1], vf1, acc[0][df]);
      acc[1][df] = mfma16(pf[1][0], vf0, acc[1][df]);
      acc[1][df] = mfma16(pf[1][1], vf1, acc[1][df]);
    }
    __builtin_amdgcn_s_setprio(0);
    if (t + 1 < nt) { asm volatile("s_waitcnt vmcnt(0)" ::: "memory"); }
    __builtin_amdgcn_s_barrier();
  }

  #pragma unroll
  for (int g = 0; g < 2; g++){
    const float linv = 1.0f / l_run[g];
    float li[4];
    #pragma unroll
    for (int r = 0; r < 4; r++) li[r] = __shfl(linv, lhi*4 + r, 64);
    #pragma unroll
    for (int df = 0; df < 8; df++)
      #pragma unroll
      for (int r = 0; r < 4; r++){
        const size_t q = q0 + g*16 + lhi*4 + r;
        O[((size_t)(b*SQ + q))*DIM + h*HD + df*16 + lrow] = __float2bfloat16(acc[g][df][r] * li[r]);
      }
  }
}

// ---------------- host ----------------

extern "C" void kernel_launch(void* const* d_in, const int* in_sizes, int n_in,
                              void* d_out, int out_size, void* d_ws, size_t ws_size,
                              hipStream_t stream)
{
  const float* x    = (const float*)d_in[0];
  const float* e    = (const float*)d_in[1];
  const float* ctx  = (const float*)d_in[2];
  const float* modw = (const float*)d_in[3];
  const float* n1w  = (const float*)d_in[4];
  const float* n2w  = (const float*)d_in[5];
  const float* n3w  = (const float*)d_in[6];
  const float* nqw  = (const float*)d_in[7];
  const float* nkw  = (const float*)d_in[8];
  const float* fnw  = (const float*)d_in[9];
  const float* saqw = (const float*)d_in[10]; const float* saqb = (const float*)d_in[11];
  const float* sakw = (const float*)d_in[12]; const float* sakb = (const float*)d_in[13];
  const float* savw = (const float*)d_in[14]; const float* savb = (const float*)d_in[15];
  const float* saow = (const float*)d_in[16]; const float* saob = (const float*)d_in[17];
  const float* caqw = (const float*)d_in[18]; const float* caqb = (const float*)d_in[19];
  const float* cakw = (const float*)d_in[20]; const float* cakb = (const float*)d_in[21];
  const float* cavw = (const float*)d_in[22]; const float* cavb = (const float*)d_in[23];
  const float* caow = (const float*)d_in[24]; const float* caob = (const float*)d_in[25];
  const float* fw1  = (const float*)d_in[26]; const float* fb1  = (const float*)d_in[27];
  const float* fw2  = (const float*)d_in[28]; const float* fb2  = (const float*)d_in[29];
  float* out = (float*)d_out;
  (void)in_sizes; (void)n_in; (void)out_size; (void)ws_size;

  char* ws = (char*)d_ws;
  size_t off = 0;
  auto alloc = [&](size_t bytes) -> void* {
    void* p = ws + off; off = (off + bytes + 255) & ~(size_t)255; return p;
  };
  bf16*  wt   = (bf16*)alloc((size_t)FFND * DIM * 2);
  float* mod  = (float*)alloc((size_t)BATCH * 6 * DIM * 4);
  float* bcat = (float*)alloc((size_t)3 * DIM * 4);
  float* bcat2= (float*)alloc((size_t)2 * DIM * 4);
  bf16*  ctxb = (bf16*)alloc((size_t)BATCH * CLEN * DIM * 2);
  bf16*  hbuf = (bf16*)alloc((size_t)BATCH * SEQ * DIM * 2);
  bf16*  qbuf = (bf16*)alloc((size_t)BATCH * SEQ * DIM * 2);
  bf16*  kbuf = (bf16*)alloc((size_t)BATCH * SEQ * DIM * 2);
  bf16*  vtb  = (bf16*)alloc((size_t)BATCH * SEQ * DIM * 2);
  bf16*  aout = (bf16*)alloc((size_t)BATCH * SEQ * DIM * 2);
  float* xcur = (float*)alloc((size_t)BATCH * SEQ * DIM * 4);
  bf16*  hf   = (bf16*)alloc((size_t)BATCH * SEQ * FFND * 2);

  const int M = BATCH * SEQ;     // 4096
  const int Mc = BATCH * CLEN;   // 1024

  modadd_k<<<dim3(96), dim3(256), 0, stream>>>(modw, e, mod);
  f2b8_k<<<dim3(1024), dim3(256), 0, stream>>>(ctx, ctxb);
  biascat_k<<<dim3(40), dim3(256), 0, stream>>>(saqb, sakb, savb, cakb, cavb, bcat, bcat2);

  // --- self attention: fused QKV (N=6144) ---
  norm_x<1><<<dim3(M), dim3(256), 0, stream>>>(x, n1w, nullptr, mod, hbuf, SEQ);

  transpose_w3<<<dim3(DIM/64, DIM/64, 3), dim3(256), 0, stream>>>(saqw, sakw, savw, wt, DIM, DIM);
  gemm_bf16<5><<<dim3(3*DIM/256, M/128), dim3(512), 0, stream>>>(hbuf, wt, bcat, nullptr, nullptr, nullptr, qbuf, kbuf, vtb, M, 3*DIM, DIM, SEQ, 0);
  rmsnorm2_bf16_ip<<<dim3(2*M), dim3(256), 0, stream>>>(qbuf, nqw, kbuf, nkw, M);

  attn_fwd<<<dim3((SEQ/128)*HEADS*BATCH), dim3(256), 0, stream>>>(qbuf, kbuf, vtb, aout, SEQ, SEQ);

  transpose_w<<<dim3(DIM/64, DIM/64), dim3(256), 0, stream>>>(saow, wt, DIM, DIM);
  gemm_bf16<2><<<dim3(DIM/256, M/128), dim3(512), 0, stream>>>(aout, wt, saob, x, mod, xcur, nullptr, nullptr, nullptr, M, DIM, DIM, SEQ, 2);

  // --- cross attention: q gemm + fused KV gemm (N=4096) ---
  norm_x<2><<<dim3(M), dim3(256), 0, stream>>>(xcur, n2w, nullptr, mod, hbuf, SEQ);

  transpose_w3<<<dim3(DIM/64, DIM/64, 3), dim3(256), 0, stream>>>(caqw, cakw, cavw, wt, DIM, DIM);
  gemm_bf16<0><<<dim3(DIM/256, M/128), dim3(512), 0, stream>>>(hbuf, wt, caqb, nullptr, nullptr, nullptr, qbuf, nullptr, nullptr, M, DIM, DIM, SEQ, 0);
  gemm_bf16<6><<<dim3(2*DIM/256, Mc/128), dim3(512), 0, stream>>>(ctxb, wt + (size_t)DIM*DIM, bcat2, nullptr, nullptr, nullptr, nullptr, kbuf, vtb, Mc, 2*DIM, DIM, CLEN, 0);

  attn_fwd<<<dim3((SEQ/128)*HEADS*BATCH), dim3(256), 0, stream>>>(qbuf, kbuf, vtb, aout, SEQ, CLEN);

  transpose_w<<<dim3(DIM/64, DIM/64), dim3(256), 0, stream>>>(caow, wt, DIM, DIM);
  gemm_bf16<3><<<dim3(DIM/256, M/128), dim3(512), 0, stream>>>(aout, wt, caob, nullptr, nullptr, xcur, nullptr, nullptr, nullptr, M, DIM, DIM, SEQ, 0);

  // --- FFN ---
  norm_x<3><<<dim3(M), dim3(256), 0, stream>>>(xcur, n3w, fnw, mod, hbuf, SEQ);

  transpose_w<<<dim3(FFND/64, DIM/64), dim3(256), 0, stream>>>(fw1, wt, DIM, FFND);
  gemm_bf16<4><<<dim3(FFND/256, M/128), dim3(512), 0, stream>>>(hbuf, wt, fb1, nullptr, nullptr, nullptr, hf, nullptr, nullptr, M, FFND, DIM, SEQ, 0);

  transpose_w<<<dim3(DIM/64, FFND/64), dim3(256), 0, stream>>>(fw2, wt, FFND, DIM);
  gemm_bf16<2><<<dim3(DIM/256, M/128), dim3(512), 0, stream>>>(hf, wt, fb2, xcur, mod, out, nullptr, nullptr, nullptr, M, DIM, FFND, SEQ, 5);
}

// Round 20
// 885.816 us; speedup vs baseline: 1.0774x; 1.0023x over previous
//
#include <hip/hip_runtime.h>
#include <hip/hip_bf16.h>
#include <cstdint>

#define DIM   2048
#define HEADS 16
#define HD    128
#define SEQ   2048
#define CLEN  512
#define FFND  8192
#define BATCH 2

using bf16 = __hip_bfloat16;
typedef __attribute__((ext_vector_type(8))) short  short8;
typedef __attribute__((ext_vector_type(4))) short  short4v;
typedef __attribute__((ext_vector_type(4))) float  f32x4;
typedef __attribute__((ext_vector_type(8))) __bf16 bf16x8;

__device__ __forceinline__ short f2bs(float f){ bf16 h = __float2bfloat16(f); return __builtin_bit_cast(short, h); }
__device__ __forceinline__ float bs2f(short s){ return __builtin_bit_cast(float, (uint32_t)((uint16_t)s) << 16); }

__device__ __forceinline__ f32x4 mfma16(short8 a, short8 b, f32x4 c){
  return __builtin_amdgcn_mfma_f32_16x16x32_bf16(
      __builtin_bit_cast(bf16x8, a), __builtin_bit_cast(bf16x8, b), c, 0, 0, 0);
}

__device__ __forceinline__ void gload_lds16(const void* g, const void* l){
  __builtin_amdgcn_global_load_lds(
      (const __attribute__((address_space(1))) void*)(uintptr_t)g,
      (__attribute__((address_space(3))) void*)(uint32_t)(uintptr_t)l, 16, 0, 0);
}

__device__ __forceinline__ float block_sum(float v, float* sbuf, int tid){
  #pragma unroll
  for (int m = 32; m >= 1; m >>= 1) v += __shfl_xor(v, m, 64);
  const int w = tid >> 6;
  if ((tid & 63) == 0) sbuf[w] = v;
  __syncthreads();
  float r = sbuf[0] + sbuf[1] + sbuf[2] + sbuf[3];
  __syncthreads();
  return r;
}

// ---------------- small elementwise kernels ----------------

__global__ void modadd_k(const float* __restrict__ m, const float* __restrict__ e,
                         float* __restrict__ out){
  int i = blockIdx.x * 256 + threadIdx.x;
  out[i] = m[i % (6 * DIM)] + e[i];
}

__global__ void f2b8_k(const float* __restrict__ in, bf16* __restrict__ out){
  int i = blockIdx.x * 256 + threadIdx.x;
  const float4* p = (const float4*)in;
  float4 a = p[2*i], c = p[2*i+1];
  short8 o;
  o[0]=f2bs(a.x); o[1]=f2bs(a.y); o[2]=f2bs(a.z); o[3]=f2bs(a.w);
  o[4]=f2bs(c.x); o[5]=f2bs(c.y); o[6]=f2bs(c.z); o[7]=f2bs(c.w);
  *((short8*)out + i) = o;
}

// bcat[0:3*DIM) = saqb||sakb||savb ; bcat2[0:2*DIM) = cakb||cavb
__global__ void biascat_k(const float* __restrict__ b0, const float* __restrict__ b1,
                          const float* __restrict__ b2, const float* __restrict__ c0,
                          const float* __restrict__ c1, float* __restrict__ bcat,
                          float* __restrict__ bcat2){
  int i = blockIdx.x * 256 + threadIdx.x;
  if (i < 3*DIM){
    const float* src = (i < DIM) ? b0 : (i < 2*DIM) ? b1 : b2;
    bcat[i] = src[i & (DIM-1)];
  } else {
    int j = i - 3*DIM;
    const float* src = (j < DIM) ? c0 : c1;
    bcat2[j] = src[j & (DIM-1)];
  }
}

// transpose + f32->bf16: W[K][N] -> Wt[N][K]; 64x64 tiles, short4 (8B) writes
__global__ __launch_bounds__(256) void transpose_w(const float* __restrict__ W,
                                                   bf16* __restrict__ Wt, int K, int N){
  __shared__ float tile[64][65];
  const int tx = threadIdx.x & 63, ty = threadIdx.x >> 6;
  const size_t k0 = (size_t)blockIdx.y * 64, n0 = (size_t)blockIdx.x * 64;
  #pragma unroll
  for (int i = 0; i < 16; i++)
    tile[ty + i*4][tx] = W[(k0 + ty + i*4) * (size_t)N + n0 + tx];
  __syncthreads();
  const int kx = threadIdx.x & 15;
  const int ny = threadIdx.x >> 4;
  #pragma unroll
  for (int i = 0; i < 4; i++){
    const int n = ny + i*16;
    short4v o;
    #pragma unroll
    for (int j = 0; j < 4; j++) o[j] = f2bs(tile[kx*4 + j][n]);
    *(short4v*)&Wt[(n0 + n) * (size_t)K + k0 + kx*4] = o;
  }
}

// 3 square transposes in one launch (blockIdx.z selects source; dst offset z*K*N)
__global__ __launch_bounds__(256) void transpose_w3(const float* __restrict__ W0,
    const float* __restrict__ W1, const float* __restrict__ W2,
    bf16* __restrict__ Wt, int K, int N){
  __shared__ float tile[64][65];
  const float* W = (blockIdx.z == 0) ? W0 : (blockIdx.z == 1) ? W1 : W2;
  bf16* dst = Wt + (size_t)blockIdx.z * K * N;
  const int tx = threadIdx.x & 63, ty = threadIdx.x >> 6;
  const size_t k0 = (size_t)blockIdx.y * 64, n0 = (size_t)blockIdx.x * 64;
  #pragma unroll
  for (int i = 0; i < 16; i++)
    tile[ty + i*4][tx] = W[(k0 + ty + i*4) * (size_t)N + n0 + tx];
  __syncthreads();
  const int kx = threadIdx.x & 15;
  const int ny = threadIdx.x >> 4;
  #pragma unroll
  for (int i = 0; i < 4; i++){
    const int n = ny + i*16;
    short4v o;
    #pragma unroll
    for (int j = 0; j < 4; j++) o[j] = f2bs(tile[kx*4 + j][n]);
    *(short4v*)&dst[(n0 + n) * (size_t)K + k0 + kx*4] = o;
  }
}

// MODE 1: out = bf16( rms(x)*w1*(1+e1) + e0 )
// MODE 2: out = bf16( rms(x)*w1 )
// MODE 3: t = rms_a(x)*w1*(1+e4)+e3 ; out = bf16( rms_b(t)*w2 )
template<int MODE>
__global__ __launch_bounds__(256) void norm_x(const float* __restrict__ x,
    const float* __restrict__ w1, const float* __restrict__ w2,
    const float* __restrict__ mod, bf16* __restrict__ out, int S)
{
  const int row = blockIdx.x, tid = threadIdx.x;
  const int b = row / S;
  __shared__ float sbuf[4];
  const float* xr = x + (size_t)row * DIM;
  float v[8];
  #pragma unroll
  for (int i = 0; i < 2; i++){
    float4 t = *(const float4*)(xr + i*1024 + tid*4);
    v[i*4+0]=t.x; v[i*4+1]=t.y; v[i*4+2]=t.z; v[i*4+3]=t.w;
  }
  float ss = 0.f;
  #pragma unroll
  for (int j = 0; j < 8; j++) ss += v[j]*v[j];
  ss = block_sum(ss, sbuf, tid);
  const float r = rsqrtf(ss * (1.0f/DIM) + 1e-6f);
  const float* mb = mod + (size_t)b * 6 * DIM;
  float t8[8];
  #pragma unroll
  for (int i = 0; i < 2; i++)
    #pragma unroll
    for (int j = 0; j < 4; j++){
      int n = i*1024 + tid*4 + j;
      float val = v[i*4+j] * r * w1[n];
      if (MODE == 1) val = val * (1.f + mb[DIM + n]) + mb[n];
      if (MODE == 3) val = val * (1.f + mb[4*DIM + n]) + mb[3*DIM + n];
      t8[i*4+j] = val;
    }
  if (MODE == 3){
    float s2 = 0.f;
    #pragma unroll
    for (int j = 0; j < 8; j++) s2 += t8[j]*t8[j];
    s2 = block_sum(s2, sbuf, tid);
    const float r2 = rsqrtf(s2 * (1.0f/DIM) + 1e-6f);
    #pragma unroll
    for (int i = 0; i < 2; i++)
      #pragma unroll
      for (int j = 0; j < 4; j++){
        int n = i*1024 + tid*4 + j;
        t8[i*4+j] = t8[i*4+j] * r2 * w2[n];
      }
  }
  #pragma unroll
  for (int i = 0; i < 2; i++){
    short4v o;
    #pragma unroll
    for (int j = 0; j < 4; j++) o[j] = f2bs(t8[i*4+j]);
    *(short4v*)(out + (size_t)row*DIM + i*1024 + tid*4) = o;
  }
}

// in-place rmsnorm on bf16 rows: rows [0,M) -> xq with wq, rows [M,2M) -> xk with wk
__global__ __launch_bounds__(256) void rmsnorm2_bf16_ip(bf16* __restrict__ xq, const float* __restrict__ wq,
                                                        bf16* __restrict__ xk, const float* __restrict__ wk,
                                                        int M){
  const int row = blockIdx.x, tid = threadIdx.x;
  __shared__ float sbuf[4];
  bf16* xr; const float* w;
  if (row < M){ xr = xq + (size_t)row * DIM; w = wq; }
  else        { xr = xk + (size_t)(row - M) * DIM; w = wk; }
  short8 v = *(const short8*)(xr + tid*8);
  float f[8]; float ss = 0.f;
  #pragma unroll
  for (int j = 0; j < 8; j++){ f[j] = bs2f(v[j]); ss += f[j]*f[j]; }
  ss = block_sum(ss, sbuf, tid);
  const float r = rsqrtf(ss * (1.0f/DIM) + 1e-6f);
  short8 o;
  #pragma unroll
  for (int j = 0; j < 8; j++) o[j] = f2bs(f[j] * r * w[tid*8 + j]);
  *(short8*)(xr + tid*8) = o;
}

// ---------------- GEMM (r17 champion + T1 n-major XCD chunking) ----------------
// BM=128, BN=256, BK=32; 512 threads = 8 waves (2M x 4N), per-wave 64x64.
// Triple-buffered LDS, counted vmcnt(3), seg-XOR swizzle (0 conflicts), setprio.
// T1: flatten grid, bijective XCD chunk f=(p&7)*(nwg/8)+(p>>3); n-major within
// chunk (bx = f/My, by = f%My) so each XCD owns contiguous B-columns ->
// B-panels fetched ~once per XCD, A-rereads served by L3. All grids %8==0.
// EPI 0: outb=bf16  1: Vt layout  2: outf=xin+v*mod[eidx]  3: outf+=v
// EPI 4: gelu->outb  5: QKV split (N=6144)  6: KV split (N=4096)
#define GBUF 24576
template<int EPI>
__global__ __launch_bounds__(512, 2) void gemm_bf16(
    const bf16* __restrict__ A, const bf16* __restrict__ Bt,
    const float* __restrict__ bias, const float* __restrict__ xin,
    const float* __restrict__ mod, float* __restrict__ outf,
    bf16* __restrict__ outb, bf16* __restrict__ out1, bf16* __restrict__ out2,
    int M, int N, int K, int S_tok, int eidx)
{
  __shared__ __align__(16) char lds[3][GBUF];
  const int tid = threadIdx.x;
  const int w = tid >> 6, l = tid & 63;
  const int lrow = l & 15, lhi = l >> 4;
  const int wm = w >> 2, wn = w & 3;
  // T1 bijective XCD chunking, n-major within chunk
  const int My = M >> 7;                       // blocks along M
  const int nwg = (N >> 8) * My;
  const int p = (int)blockIdx.x;
  const int fz = (p & 7) * (nwg >> 3) + (p >> 3);
  const size_t m0 = (size_t)(fz % My) * 128;
  const size_t n0 = (size_t)(fz / My) * 256;

  f32x4 acc[4][4] = {};

  auto gofs = [&](int sid){ return (size_t)(sid >> 2) * K + (size_t)(((sid & 3) ^ ((sid >> 3) & 3)) * 8); };
  const bf16* gA0 = A  + m0 * K + gofs(tid);
  const bf16* gB0 = Bt + n0 * K + gofs(tid);
  const bf16* gB1 = Bt + n0 * K + gofs(tid + 512);

  auto stage = [&](int kt, char* buf){
    const size_t ko = (size_t)kt * 32;
    gload_lds16(gA0 + ko, buf + tid * 16);
    gload_lds16(gB0 + ko, buf + 8192 + tid * 16);
    gload_lds16(gB1 + ko, buf + 8192 + (tid + 512) * 16);
  };

  const int nt = K >> 5;
  stage(0, lds[0]);
  stage(1, lds[1]);
  asm volatile("s_waitcnt vmcnt(3)" ::: "memory");
  __builtin_amdgcn_s_barrier();
  __builtin_amdgcn_sched_barrier(0);

  const int sread = (lhi ^ ((lrow >> 1) & 3)) * 16;

  int bi = 0;
  for (int t = 0; t < nt; ++t){
    const char* br = lds[bi];
    const bool st = (t + 2 < nt);
    if (st){
      int wi = bi + 2; if (wi >= 3) wi -= 3;
      stage(t + 2, lds[wi]);
    }
    short8 af[4], bf[4];
    #pragma unroll
    for (int mi = 0; mi < 4; mi++)
      af[mi] = *(const short8*)(br + (wm*64 + mi*16 + lrow)*64 + sread);
    #pragma unroll
    for (int ni = 0; ni < 4; ni++)
      bf[ni] = *(const short8*)(br + 8192 + (wn*64 + ni*16 + lrow)*64 + sread);
    __builtin_amdgcn_s_setprio(1);
    #pragma unroll
    for (int mi = 0; mi < 4; mi++)
      #pragma unroll
      for (int ni = 0; ni < 4; ni++)
        acc[mi][ni] = mfma16(af[mi], bf[ni], acc[mi][ni]);
    __builtin_amdgcn_s_setprio(0);
    if (st)               { asm volatile("s_waitcnt vmcnt(3)" ::: "memory"); }
    else if (t + 1 < nt)  { asm volatile("s_waitcnt vmcnt(0)" ::: "memory"); }
    __builtin_amdgcn_s_barrier();
    __builtin_amdgcn_sched_barrier(0);
    bi = (bi + 1 == 3) ? 0 : bi + 1;
  }

  #pragma unroll
  for (int mi = 0; mi < 4; mi++)
    #pragma unroll
    for (int ni = 0; ni < 4; ni++)
      #pragma unroll
      for (int r = 0; r < 4; r++){
        const size_t m = m0 + wm*64 + mi*16 + lhi*4 + r;
        const size_t n = n0 + wn*64 + ni*16 + lrow;
        float v = acc[mi][ni][r] + bias[n];
        if constexpr (EPI == 0) {
          outb[m * N + n] = __float2bfloat16(v);
        } else if constexpr (EPI == 1) {
          const size_t b = m / S_tok, s = m % S_tok;
          const size_t h = n >> 7, d = n & 127;
          outb[((b*HEADS + h)*HD + d) * S_tok + s] = __float2bfloat16(v);
        } else if constexpr (EPI == 2) {
          const float ev = mod[(m / S_tok) * 6 * DIM + (size_t)eidx * DIM + n];
          outf[m * N + n] = xin[m * N + n] + v * ev;
        } else if constexpr (EPI == 3) {
          outf[m * N + n] += v;
        } else if constexpr (EPI == 4) {
          float u = 0.7978845608028654f * (v + 0.044715f * v * v * v);
          outb[m * N + n] = __float2bfloat16(0.5f * v * (1.0f + tanhf(u)));
        } else if constexpr (EPI == 5) {   // QKV split (N = 6144)
          const size_t sg = n >> 11, col = n & 2047;
          if (sg == 0)      outb[m * DIM + col] = __float2bfloat16(v);
          else if (sg == 1) out1[m * DIM + col] = __float2bfloat16(v);
          else {
            const size_t b = m / S_tok, s = m % S_tok;
            const size_t h = col >> 7, d = col & 127;
            out2[((b*HEADS + h)*HD + d) * S_tok + s] = __float2bfloat16(v);
          }
        } else {   // EPI 6: KV split (N = 4096)
          const size_t sg = n >> 11, col = n & 2047;
          if (sg == 0) out1[m * DIM + col] = __float2bfloat16(v);
          else {
            const size_t b = m / S_tok, s = m % S_tok;
            const size_t h = col >> 7, d = col & 127;
            out2[((b*HEADS + h)*HD + d) * S_tok + s] = __float2bfloat16(v);
          }
        }
      }
}

// ---------------- flash attention: 32 q-rows/wave, V single-buf LDS, setprio + defer-max ----------------
__global__ __launch_bounds__(256, 2) void attn_fwd(
    const bf16* __restrict__ Q, const bf16* __restrict__ Kp, const bf16* __restrict__ Vt,
    bf16* __restrict__ O, int SQ, int SKV)
{
  const int tid = threadIdx.x, w = tid >> 6, l = tid & 63;
  const int lrow = l & 15, lhi = l >> 4;
  const int nwg = gridDim.x;
  const int p = blockIdx.x;
  const int f = (p & 7) * (nwg >> 3) + (p >> 3);
  const int nqb = SQ >> 7;
  const int xq = f % nqb;
  const int h  = (f / nqb) % HEADS;
  const int b  = f / (nqb * HEADS);
  const int q0 = xq * 128 + w * 32;

  __shared__ __align__(16) char kls[2][16384];
  __shared__ __align__(16) char vls[16384];
  __shared__ __align__(16) bf16 P[4][2][16][72];
  const float scale = 0.08838834764831845f;

  short8 qf[2][4];
  #pragma unroll
  for (int g = 0; g < 2; g++){
    const bf16* qp = Q + ((size_t)(b*SQ + q0 + g*16 + lrow))*DIM + h*HD + lhi*8;
    #pragma unroll
    for (int ds = 0; ds < 4; ds++) qf[g][ds] = *(const short8*)(qp + ds*32);
  }

  const bf16* kg = Kp + (size_t)b*SKV*DIM + h*HD;
  const bf16* vg = Vt + (size_t)(b*HEADS + h)*HD*SKV;

  f32x4 acc[2][8] = {};
  float m_run[2] = {-INFINITY, -INFINITY}, l_run[2] = {0.f, 0.f};
  const int nt = SKV >> 6;

  auto stage_k = [&](int buf, int kv0){
    char* kd = &kls[buf][0];
    #pragma unroll
    for (int i = 0; i < 4; i++){
      int sid = i*256 + tid;
      int row = sid >> 4, sg = sid & 15;
      int gsg = sg ^ (row & 7);
      gload_lds16(kg + (size_t)(kv0 + row)*DIM + gsg*8, kd + sid*16);
    }
  };
  auto stage_v = [&](int kv0){
    #pragma unroll
    for (int i = 0; i < 4; i++){
      int sid = i*256 + tid;
      int d = sid >> 3, sg = sid & 7;
      int gsg = sg ^ (d & 7);
      gload_lds16(vg + (size_t)d*SKV + kv0 + gsg*8, &vls[0] + sid*16);
    }
  };

  stage_k(0, 0);
  stage_v(0);
  asm volatile("s_waitcnt vmcnt(0)" ::: "memory");
  __builtin_amdgcn_s_barrier();

  for (int t = 0; t < nt; ++t){
    if (t > 0)      stage_v(t * 64);
    if (t + 1 < nt) stage_k((t + 1) & 1, (t + 1) * 64);
    const char* kb = &kls[t & 1][0];

    f32x4 st[2][4] = {};
    __builtin_amdgcn_s_setprio(1);
    #pragma unroll
    for (int kvf = 0; kvf < 4; kvf++){
      const int row = kvf*16 + lrow;
      const int rx = row & 7;
      #pragma unroll
      for (int ds = 0; ds < 4; ds++){
        const int seg = (ds*4 + lhi) ^ rx;
        short8 kf = *(const short8*)(kb + row*256 + seg*16);
        st[0][kvf] = mfma16(kf, qf[0][ds], st[0][kvf]);
        st[1][kvf] = mfma16(kf, qf[1][ds], st[1][kvf]);
      }
    }
    __builtin_amdgcn_s_setprio(0);

    #pragma unroll
    for (int g = 0; g < 2; g++){
      float sv[16]; float smax = -INFINITY;
      #pragma unroll
      for (int kvf = 0; kvf < 4; kvf++)
        #pragma unroll
        for (int r = 0; r < 4; r++){
          float xv = st[g][kvf][r] * scale;
          sv[kvf*4+r] = xv; smax = fmaxf(smax, xv);
        }
      smax = fmaxf(smax, __shfl_xor(smax, 16, 64));
      smax = fmaxf(smax, __shfl_xor(smax, 32, 64));
      const bool nore = __all(smax <= m_run[g] + 8.0f);
      const float mnew = nore ? m_run[g] : fmaxf(m_run[g], smax);
      float psum = 0.f;
      #pragma unroll
      for (int i = 0; i < 16; i++){ float pe = __expf(sv[i] - mnew); sv[i] = pe; psum += pe; }
      psum += __shfl_xor(psum, 16, 64); psum += __shfl_xor(psum, 32, 64);
      #pragma unroll
      for (int kvf = 0; kvf < 4; kvf++){
        short4v o;
        #pragma unroll
        for (int r = 0; r < 4; r++) o[r] = f2bs(sv[kvf*4+r]);
        *(short4v*)&P[w][g][lrow][kvf*16 + lhi*4] = o;
      }
      if (nore){
        l_run[g] += psum;
      } else {
        const float corr = __expf(m_run[g] - mnew);
        l_run[g] = l_run[g] * corr + psum;
        m_run[g] = mnew;
        float cr[4];
        #pragma unroll
        for (int r = 0; r < 4; r++) cr[r] = __shfl(corr, lhi*4 + r, 64);
        #pragma unroll
        for (int df = 0; df < 8; df++){
          acc[g][df][0] *= cr[0]; acc[g][df][1] *= cr[1];
          acc[g][df][2] *= cr[2]; acc[g][df][3] *= cr[3];
        }
      }
    }

    if (t + 1 < nt) { asm volatile("s_waitcnt vmcnt(4)" ::: "memory"); }
    else            { asm volatile("s_waitcnt vmcnt(0)" ::: "memory"); }
    __builtin_amdgcn_s_barrier();
    asm volatile("s_waitcnt lgkmcnt(0)" ::: "memory");
    __builtin_amdgcn_sched_barrier(0);

    short8 pf[2][2];
    #pragma unroll
    for (int g = 0; g < 2; g++){
      pf[g][0] = *(const short8*)&P[w][g][lrow][lhi*8];
      pf[g][1] = *(const short8*)&P[w][g][lrow][32 + lhi*8];
    }
    __builtin_amdgcn_s_setprio(1);
    #pragma unroll
    for (int df = 0; df < 8; df++){
      const int d = df*16 + lrow;
      const int dx = d & 7;
      short8 vf0 = *(const short8*)(&vls[0] + d*128 + ((lhi)     ^ dx)*16);
      short8 vf1 = *(const short8*)(&vls[0] + d*128 + ((lhi + 4) ^ dx)*16);
      acc[0][df] = mfma16(pf[0][0], vf0, acc[0][df]);
      acc[0][df] = mfma16(pf[0][1], vf1, acc[0][df]);
      acc[1][df] = mfma16(pf[1][0], vf0, acc[1][df]);
      acc[1][df] = mfma16(pf[1][1], vf1, acc[1][df]);
    }
    __builtin_amdgcn_s_setprio(0);
    if (t + 1 < nt) { asm volatile("s_waitcnt vmcnt(0)" ::: "memory"); }
    __builtin_amdgcn_s_barrier();
  }

  #pragma unroll
  for (int g = 0; g < 2; g++){
    const float linv = 1.0f / l_run[g];
    float li[4];
    #pragma unroll
    for (int r = 0; r < 4; r++) li[r] = __shfl(linv, lhi*4 + r, 64);
    #pragma unroll
    for (int df = 0; df < 8; df++)
      #pragma unroll
      for (int r = 0; r < 4; r++){
        const size_t q = q0 + g*16 + lhi*4 + r;
        O[((size_t)(b*SQ + q))*DIM + h*HD + df*16 + lrow] = __float2bfloat16(acc[g][df][r] * li[r]);
      }
  }
}

// ---------------- host ----------------

extern "C" void kernel_launch(void* const* d_in, const int* in_sizes, int n_in,
                              void* d_out, int out_size, void* d_ws, size_t ws_size,
                              hipStream_t stream)
{
  const float* x    = (const float*)d_in[0];
  const float* e    = (const float*)d_in[1];
  const float* ctx  = (const float*)d_in[2];
  const float* modw = (const float*)d_in[3];
  const float* n1w  = (const float*)d_in[4];
  const float* n2w  = (const float*)d_in[5];
  const float* n3w  = (const float*)d_in[6];
  const float* nqw  = (const float*)d_in[7];
  const float* nkw  = (const float*)d_in[8];
  const float* fnw  = (const float*)d_in[9];
  const float* saqw = (const float*)d_in[10]; const float* saqb = (const float*)d_in[11];
  const float* sakw = (const float*)d_in[12]; const float* sakb = (const float*)d_in[13];
  const float* savw = (const float*)d_in[14]; const float* savb = (const float*)d_in[15];
  const float* saow = (const float*)d_in[16]; const float* saob = (const float*)d_in[17];
  const float* caqw = (const float*)d_in[18]; const float* caqb = (const float*)d_in[19];
  const float* cakw = (const float*)d_in[20]; const float* cakb = (const float*)d_in[21];
  const float* cavw = (const float*)d_in[22]; const float* cavb = (const float*)d_in[23];
  const float* caow = (const float*)d_in[24]; const float* caob = (const float*)d_in[25];
  const float* fw1  = (const float*)d_in[26]; const float* fb1  = (const float*)d_in[27];
  const float* fw2  = (const float*)d_in[28]; const float* fb2  = (const float*)d_in[29];
  float* out = (float*)d_out;
  (void)in_sizes; (void)n_in; (void)out_size; (void)ws_size;

  char* ws = (char*)d_ws;
  size_t off = 0;
  auto alloc = [&](size_t bytes) -> void* {
    void* p = ws + off; off = (off + bytes + 255) & ~(size_t)255; return p;
  };
  bf16*  wt   = (bf16*)alloc((size_t)FFND * DIM * 2);
  float* mod  = (float*)alloc((size_t)BATCH * 6 * DIM * 4);
  float* bcat = (float*)alloc((size_t)3 * DIM * 4);
  float* bcat2= (float*)alloc((size_t)2 * DIM * 4);
  bf16*  ctxb = (bf16*)alloc((size_t)BATCH * CLEN * DIM * 2);
  bf16*  hbuf = (bf16*)alloc((size_t)BATCH * SEQ * DIM * 2);
  bf16*  qbuf = (bf16*)alloc((size_t)BATCH * SEQ * DIM * 2);
  bf16*  kbuf = (bf16*)alloc((size_t)BATCH * SEQ * DIM * 2);
  bf16*  vtb  = (bf16*)alloc((size_t)BATCH * SEQ * DIM * 2);
  bf16*  aout = (bf16*)alloc((size_t)BATCH * SEQ * DIM * 2);
  float* xcur = (float*)alloc((size_t)BATCH * SEQ * DIM * 4);
  bf16*  hf   = (bf16*)alloc((size_t)BATCH * SEQ * FFND * 2);

  const int M = BATCH * SEQ;     // 4096
  const int Mc = BATCH * CLEN;   // 1024

  modadd_k<<<dim3(96), dim3(256), 0, stream>>>(modw, e, mod);
  f2b8_k<<<dim3(1024), dim3(256), 0, stream>>>(ctx, ctxb);
  biascat_k<<<dim3(40), dim3(256), 0, stream>>>(saqb, sakb, savb, cakb, cavb, bcat, bcat2);

  // --- self attention: fused QKV (N=6144) ---
  norm_x<1><<<dim3(M), dim3(256), 0, stream>>>(x, n1w, nullptr, mod, hbuf, SEQ);

  transpose_w3<<<dim3(DIM/64, DIM/64, 3), dim3(256), 0, stream>>>(saqw, sakw, savw, wt, DIM, DIM);
  gemm_bf16<5><<<dim3((3*DIM/256)*(M/128)), dim3(512), 0, stream>>>(hbuf, wt, bcat, nullptr, nullptr, nullptr, qbuf, kbuf, vtb, M, 3*DIM, DIM, SEQ, 0);
  rmsnorm2_bf16_ip<<<dim3(2*M), dim3(256), 0, stream>>>(qbuf, nqw, kbuf, nkw, M);

  attn_fwd<<<dim3((SEQ/128)*HEADS*BATCH), dim3(256), 0, stream>>>(qbuf, kbuf, vtb, aout, SEQ, SEQ);

  transpose_w<<<dim3(DIM/64, DIM/64), dim3(256), 0, stream>>>(saow, wt, DIM, DIM);
  gemm_bf16<2><<<dim3((DIM/256)*(M/128)), dim3(512), 0, stream>>>(aout, wt, saob, x, mod, xcur, nullptr, nullptr, nullptr, M, DIM, DIM, SEQ, 2);

  // --- cross attention: q gemm + fused KV gemm (N=4096) ---
  norm_x<2><<<dim3(M), dim3(256), 0, stream>>>(xcur, n2w, nullptr, mod, hbuf, SEQ);

  transpose_w3<<<dim3(DIM/64, DIM/64, 3), dim3(256), 0, stream>>>(caqw, cakw, cavw, wt, DIM, DIM);
  gemm_bf16<0><<<dim3((DIM/256)*(M/128)), dim3(512), 0, stream>>>(hbuf, wt, caqb, nullptr, nullptr, nullptr, qbuf, nullptr, nullptr, M, DIM, DIM, SEQ, 0);
  gemm_bf16<6><<<dim3((2*DIM/256)*(Mc/128)), dim3(512), 0, stream>>>(ctxb, wt + (size_t)DIM*DIM, bcat2, nullptr, nullptr, nullptr, nullptr, kbuf, vtb, Mc, 2*DIM, DIM, CLEN, 0);

  attn_fwd<<<dim3((SEQ/128)*HEADS*BATCH), dim3(256), 0, stream>>>(qbuf, kbuf, vtb, aout, SEQ, CLEN);

  transpose_w<<<dim3(DIM/64, DIM/64), dim3(256), 0, stream>>>(caow, wt, DIM, DIM);
  gemm_bf16<3><<<dim3((DIM/256)*(M/128)), dim3(512), 0, stream>>>(aout, wt, caob, nullptr, nullptr, xcur, nullptr, nullptr, nullptr, M, DIM, DIM, SEQ, 0);

  // --- FFN ---
  norm_x<3><<<dim3(M), dim3(256), 0, stream>>>(xcur, n3w, fnw, mod, hbuf, SEQ);

  transpose_w<<<dim3(FFND/64, DIM/64), dim3(256), 0, stream>>>(fw1, wt, DIM, FFND);
  gemm_bf16<4><<<dim3((FFND/256)*(M/128)), dim3(512), 0, stream>>>(hbuf, wt, fb1, nullptr, nullptr, nullptr, hf, nullptr, nullptr, M, FFND, DIM, SEQ, 0);

  transpose_w<<<dim3(DIM/64, FFND/64), dim3(256), 0, stream>>>(fw2, wt, FFND, DIM);
  gemm_bf16<2><<<dim3((DIM/256)*(M/128)), dim3(512), 0, stream>>>(hf, wt, fb2, xcur, mod, out, nullptr, nullptr, nullptr, M, DIM, FFND, SEQ, 5);
}

// Round 21
// 875.078 us; speedup vs baseline: 1.0906x; 1.0123x over previous
//
#include <hip/hip_runtime.h>
#include <hip/hip_bf16.h>
#include <cstdint>

#define DIM   2048
#define HEADS 16
#define HD    128
#define SEQ   2048
#define CLEN  512
#define FFND  8192
#define BATCH 2

using bf16 = __hip_bfloat16;
typedef __attribute__((ext_vector_type(8))) short  short8;
typedef __attribute__((ext_vector_type(4))) short  short4v;
typedef __attribute__((ext_vector_type(4))) float  f32x4;
typedef __attribute__((ext_vector_type(8))) __bf16 bf16x8;

__device__ __forceinline__ short f2bs(float f){ bf16 h = __float2bfloat16(f); return __builtin_bit_cast(short, h); }
__device__ __forceinline__ float bs2f(short s){ return __builtin_bit_cast(float, (uint32_t)((uint16_t)s) << 16); }

__device__ __forceinline__ f32x4 mfma16(short8 a, short8 b, f32x4 c){
  return __builtin_amdgcn_mfma_f32_16x16x32_bf16(
      __builtin_bit_cast(bf16x8, a), __builtin_bit_cast(bf16x8, b), c, 0, 0, 0);
}

__device__ __forceinline__ void gload_lds16(const void* g, const void* l){
  __builtin_amdgcn_global_load_lds(
      (const __attribute__((address_space(1))) void*)(uintptr_t)g,
      (__attribute__((address_space(3))) void*)(uint32_t)(uintptr_t)l, 16, 0, 0);
}

__device__ __forceinline__ float block_sum(float v, float* sbuf, int tid){
  #pragma unroll
  for (int m = 32; m >= 1; m >>= 1) v += __shfl_xor(v, m, 64);
  const int w = tid >> 6;
  if ((tid & 63) == 0) sbuf[w] = v;
  __syncthreads();
  float r = sbuf[0] + sbuf[1] + sbuf[2] + sbuf[3];
  __syncthreads();
  return r;
}

// ---------------- small elementwise kernels ----------------

__global__ void modadd_k(const float* __restrict__ m, const float* __restrict__ e,
                         float* __restrict__ out){
  int i = blockIdx.x * 256 + threadIdx.x;
  out[i] = m[i % (6 * DIM)] + e[i];
}

__global__ void f2b8_k(const float* __restrict__ in, bf16* __restrict__ out){
  int i = blockIdx.x * 256 + threadIdx.x;
  const float4* p = (const float4*)in;
  float4 a = p[2*i], c = p[2*i+1];
  short8 o;
  o[0]=f2bs(a.x); o[1]=f2bs(a.y); o[2]=f2bs(a.z); o[3]=f2bs(a.w);
  o[4]=f2bs(c.x); o[5]=f2bs(c.y); o[6]=f2bs(c.z); o[7]=f2bs(c.w);
  *((short8*)out + i) = o;
}

// bcat[0:3*DIM) = saqb||sakb||savb ; bcat2[0:2*DIM) = cakb||cavb
__global__ void biascat_k(const float* __restrict__ b0, const float* __restrict__ b1,
                          const float* __restrict__ b2, const float* __restrict__ c0,
                          const float* __restrict__ c1, float* __restrict__ bcat,
                          float* __restrict__ bcat2){
  int i = blockIdx.x * 256 + threadIdx.x;
  if (i < 3*DIM){
    const float* src = (i < DIM) ? b0 : (i < 2*DIM) ? b1 : b2;
    bcat[i] = src[i & (DIM-1)];
  } else {
    int j = i - 3*DIM;
    const float* src = (j < DIM) ? c0 : c1;
    bcat2[j] = src[j & (DIM-1)];
  }
}

// transpose + f32->bf16: W[K][N] -> Wt[N][K]; 64x64 tiles, short4 (8B) writes
__global__ __launch_bounds__(256) void transpose_w(const float* __restrict__ W,
                                                   bf16* __restrict__ Wt, int K, int N){
  __shared__ float tile[64][65];
  const int tx = threadIdx.x & 63, ty = threadIdx.x >> 6;
  const size_t k0 = (size_t)blockIdx.y * 64, n0 = (size_t)blockIdx.x * 64;
  #pragma unroll
  for (int i = 0; i < 16; i++)
    tile[ty + i*4][tx] = W[(k0 + ty + i*4) * (size_t)N + n0 + tx];
  __syncthreads();
  const int kx = threadIdx.x & 15;
  const int ny = threadIdx.x >> 4;
  #pragma unroll
  for (int i = 0; i < 4; i++){
    const int n = ny + i*16;
    short4v o;
    #pragma unroll
    for (int j = 0; j < 4; j++) o[j] = f2bs(tile[kx*4 + j][n]);
    *(short4v*)&Wt[(n0 + n) * (size_t)K + k0 + kx*4] = o;
  }
}

// 3 square transposes in one launch (blockIdx.z selects source; dst offset z*K*N)
__global__ __launch_bounds__(256) void transpose_w3(const float* __restrict__ W0,
    const float* __restrict__ W1, const float* __restrict__ W2,
    bf16* __restrict__ Wt, int K, int N){
  __shared__ float tile[64][65];
  const float* W = (blockIdx.z == 0) ? W0 : (blockIdx.z == 1) ? W1 : W2;
  bf16* dst = Wt + (size_t)blockIdx.z * K * N;
  const int tx = threadIdx.x & 63, ty = threadIdx.x >> 6;
  const size_t k0 = (size_t)blockIdx.y * 64, n0 = (size_t)blockIdx.x * 64;
  #pragma unroll
  for (int i = 0; i < 16; i++)
    tile[ty + i*4][tx] = W[(k0 + ty + i*4) * (size_t)N + n0 + tx];
  __syncthreads();
  const int kx = threadIdx.x & 15;
  const int ny = threadIdx.x >> 4;
  #pragma unroll
  for (int i = 0; i < 4; i++){
    const int n = ny + i*16;
    short4v o;
    #pragma unroll
    for (int j = 0; j < 4; j++) o[j] = f2bs(tile[kx*4 + j][n]);
    *(short4v*)&dst[(n0 + n) * (size_t)K + k0 + kx*4] = o;
  }
}

// MODE 1 only (f32 input x): out = bf16( rms(x)*w1*(1+e1) + e0 )
__global__ __launch_bounds__(256) void norm_x(const float* __restrict__ x,
    const float* __restrict__ w1, const float* __restrict__ mod,
    bf16* __restrict__ out, int S)
{
  const int row = blockIdx.x, tid = threadIdx.x;
  const int b = row / S;
  __shared__ float sbuf[4];
  const float* xr = x + (size_t)row * DIM;
  float v[8];
  #pragma unroll
  for (int i = 0; i < 2; i++){
    float4 t = *(const float4*)(xr + i*1024 + tid*4);
    v[i*4+0]=t.x; v[i*4+1]=t.y; v[i*4+2]=t.z; v[i*4+3]=t.w;
  }
  float ss = 0.f;
  #pragma unroll
  for (int j = 0; j < 8; j++) ss += v[j]*v[j];
  ss = block_sum(ss, sbuf, tid);
  const float r = rsqrtf(ss * (1.0f/DIM) + 1e-6f);
  const float* mb = mod + (size_t)b * 6 * DIM;
  #pragma unroll
  for (int i = 0; i < 2; i++){
    short4v o;
    #pragma unroll
    for (int j = 0; j < 4; j++){
      int n = i*1024 + tid*4 + j;
      float val = v[i*4+j] * r * w1[n];
      val = val * (1.f + mb[DIM + n]) + mb[n];
      o[j] = f2bs(val);
    }
    *(short4v*)(out + (size_t)row*DIM + i*1024 + tid*4) = o;
  }
}

// bf16-input norms (residual stream in bf16):
// MODE 2: out = bf16( rms(x)*w1 )
// MODE 3: t = rms_a(x)*w1*(1+e4)+e3 ; out = bf16( rms_b(t)*w2 )
template<int MODE>
__global__ __launch_bounds__(256) void norm_xb(const bf16* __restrict__ x,
    const float* __restrict__ w1, const float* __restrict__ w2,
    const float* __restrict__ mod, bf16* __restrict__ out, int S)
{
  const int row = blockIdx.x, tid = threadIdx.x;
  const int b = row / S;
  __shared__ float sbuf[4];
  const bf16* xr = x + (size_t)row * DIM;
  short8 vv = *(const short8*)(xr + tid*8);
  float v[8]; float ss = 0.f;
  #pragma unroll
  for (int j = 0; j < 8; j++){ v[j] = bs2f(vv[j]); ss += v[j]*v[j]; }
  ss = block_sum(ss, sbuf, tid);
  const float r = rsqrtf(ss * (1.0f/DIM) + 1e-6f);
  const float* mb = mod + (size_t)b * 6 * DIM;
  float t8[8];
  #pragma unroll
  for (int j = 0; j < 8; j++){
    int n = tid*8 + j;
    float val = v[j] * r * w1[n];
    if (MODE == 3) val = val * (1.f + mb[4*DIM + n]) + mb[3*DIM + n];
    t8[j] = val;
  }
  if (MODE == 3){
    float s2 = 0.f;
    #pragma unroll
    for (int j = 0; j < 8; j++) s2 += t8[j]*t8[j];
    s2 = block_sum(s2, sbuf, tid);
    const float r2 = rsqrtf(s2 * (1.0f/DIM) + 1e-6f);
    #pragma unroll
    for (int j = 0; j < 8; j++) t8[j] = t8[j] * r2 * w2[tid*8 + j];
  }
  short8 o;
  #pragma unroll
  for (int j = 0; j < 8; j++) o[j] = f2bs(t8[j]);
  *(short8*)(out + (size_t)row*DIM + tid*8) = o;
}

// in-place rmsnorm on bf16 rows: rows [0,M) -> xq with wq, rows [M,2M) -> xk with wk
__global__ __launch_bounds__(256) void rmsnorm2_bf16_ip(bf16* __restrict__ xq, const float* __restrict__ wq,
                                                        bf16* __restrict__ xk, const float* __restrict__ wk,
                                                        int M){
  const int row = blockIdx.x, tid = threadIdx.x;
  __shared__ float sbuf[4];
  bf16* xr; const float* w;
  if (row < M){ xr = xq + (size_t)row * DIM; w = wq; }
  else        { xr = xk + (size_t)(row - M) * DIM; w = wk; }
  short8 v = *(const short8*)(xr + tid*8);
  float f[8]; float ss = 0.f;
  #pragma unroll
  for (int j = 0; j < 8; j++){ f[j] = bs2f(v[j]); ss += f[j]*f[j]; }
  ss = block_sum(ss, sbuf, tid);
  const float r = rsqrtf(ss * (1.0f/DIM) + 1e-6f);
  short8 o;
  #pragma unroll
  for (int j = 0; j < 8; j++) o[j] = f2bs(f[j] * r * w[tid*8 + j]);
  *(short8*)(xr + tid*8) = o;
}

// ---------------- GEMM (r17 champion + T1 n-major XCD chunking) ----------------
// BM=128, BN=256, BK=32; 512 threads = 8 waves (2M x 4N), per-wave 64x64.
// Triple-buffered LDS, counted vmcnt(3), seg-XOR swizzle (0 conflicts), setprio.
// EPI 0: outb=bf16(v)                 1: Vt layout
// EPI 2: outb = bf16(xin[f32] + v*mod[eidx])   (residual -> bf16 stream)
// EPI 3: outb = bf16(bf2f(outb) + v)           (in-place bf16 residual +=)
// EPI 4: gelu->outb                   5: QKV split (N=6144)
// EPI 6: KV split (N=4096)
// EPI 7: outf = bf2f(out1[bf16 xin]) + v*mod[eidx]  (final f32 output)
#define GBUF 24576
template<int EPI>
__global__ __launch_bounds__(512, 2) void gemm_bf16(
    const bf16* __restrict__ A, const bf16* __restrict__ Bt,
    const float* __restrict__ bias, const float* __restrict__ xin,
    const float* __restrict__ mod, float* __restrict__ outf,
    bf16* __restrict__ outb, bf16* __restrict__ out1, bf16* __restrict__ out2,
    int M, int N, int K, int S_tok, int eidx)
{
  __shared__ __align__(16) char lds[3][GBUF];
  const int tid = threadIdx.x;
  const int w = tid >> 6, l = tid & 63;
  const int lrow = l & 15, lhi = l >> 4;
  const int wm = w >> 2, wn = w & 3;
  const int My = M >> 7;
  const int nwg = (N >> 8) * My;
  const int p = (int)blockIdx.x;
  const int fz = (p & 7) * (nwg >> 3) + (p >> 3);
  const size_t m0 = (size_t)(fz % My) * 128;
  const size_t n0 = (size_t)(fz / My) * 256;

  f32x4 acc[4][4] = {};

  auto gofs = [&](int sid){ return (size_t)(sid >> 2) * K + (size_t)(((sid & 3) ^ ((sid >> 3) & 3)) * 8); };
  const bf16* gA0 = A  + m0 * K + gofs(tid);
  const bf16* gB0 = Bt + n0 * K + gofs(tid);
  const bf16* gB1 = Bt + n0 * K + gofs(tid + 512);

  auto stage = [&](int kt, char* buf){
    const size_t ko = (size_t)kt * 32;
    gload_lds16(gA0 + ko, buf + tid * 16);
    gload_lds16(gB0 + ko, buf + 8192 + tid * 16);
    gload_lds16(gB1 + ko, buf + 8192 + (tid + 512) * 16);
  };

  const int nt = K >> 5;
  stage(0, lds[0]);
  stage(1, lds[1]);
  asm volatile("s_waitcnt vmcnt(3)" ::: "memory");
  __builtin_amdgcn_s_barrier();
  __builtin_amdgcn_sched_barrier(0);

  const int sread = (lhi ^ ((lrow >> 1) & 3)) * 16;

  int bi = 0;
  for (int t = 0; t < nt; ++t){
    const char* br = lds[bi];
    const bool st = (t + 2 < nt);
    if (st){
      int wi = bi + 2; if (wi >= 3) wi -= 3;
      stage(t + 2, lds[wi]);
    }
    short8 af[4], bf[4];
    #pragma unroll
    for (int mi = 0; mi < 4; mi++)
      af[mi] = *(const short8*)(br + (wm*64 + mi*16 + lrow)*64 + sread);
    #pragma unroll
    for (int ni = 0; ni < 4; ni++)
      bf[ni] = *(const short8*)(br + 8192 + (wn*64 + ni*16 + lrow)*64 + sread);
    __builtin_amdgcn_s_setprio(1);
    #pragma unroll
    for (int mi = 0; mi < 4; mi++)
      #pragma unroll
      for (int ni = 0; ni < 4; ni++)
        acc[mi][ni] = mfma16(af[mi], bf[ni], acc[mi][ni]);
    __builtin_amdgcn_s_setprio(0);
    if (st)               { asm volatile("s_waitcnt vmcnt(3)" ::: "memory"); }
    else if (t + 1 < nt)  { asm volatile("s_waitcnt vmcnt(0)" ::: "memory"); }
    __builtin_amdgcn_s_barrier();
    __builtin_amdgcn_sched_barrier(0);
    bi = (bi + 1 == 3) ? 0 : bi + 1;
  }

  #pragma unroll
  for (int mi = 0; mi < 4; mi++)
    #pragma unroll
    for (int ni = 0; ni < 4; ni++)
      #pragma unroll
      for (int r = 0; r < 4; r++){
        const size_t m = m0 + wm*64 + mi*16 + lhi*4 + r;
        const size_t n = n0 + wn*64 + ni*16 + lrow;
        float v = acc[mi][ni][r] + bias[n];
        if constexpr (EPI == 0) {
          outb[m * N + n] = __float2bfloat16(v);
        } else if constexpr (EPI == 1) {
          const size_t b = m / S_tok, s = m % S_tok;
          const size_t h = n >> 7, d = n & 127;
          outb[((b*HEADS + h)*HD + d) * S_tok + s] = __float2bfloat16(v);
        } else if constexpr (EPI == 2) {
          const float ev = mod[(m / S_tok) * 6 * DIM + (size_t)eidx * DIM + n];
          outb[m * N + n] = __float2bfloat16(xin[m * N + n] + v * ev);
        } else if constexpr (EPI == 3) {
          const float xv = __bfloat162float(outb[m * N + n]);
          outb[m * N + n] = __float2bfloat16(xv + v);
        } else if constexpr (EPI == 4) {
          float u = 0.7978845608028654f * (v + 0.044715f * v * v * v);
          outb[m * N + n] = __float2bfloat16(0.5f * v * (1.0f + tanhf(u)));
        } else if constexpr (EPI == 5) {   // QKV split (N = 6144)
          const size_t sg = n >> 11, col = n & 2047;
          if (sg == 0)      outb[m * DIM + col] = __float2bfloat16(v);
          else if (sg == 1) out1[m * DIM + col] = __float2bfloat16(v);
          else {
            const size_t b = m / S_tok, s = m % S_tok;
            const size_t h = col >> 7, d = col & 127;
            out2[((b*HEADS + h)*HD + d) * S_tok + s] = __float2bfloat16(v);
          }
        } else if constexpr (EPI == 6) {   // KV split (N = 4096)
          const size_t sg = n >> 11, col = n & 2047;
          if (sg == 0) out1[m * DIM + col] = __float2bfloat16(v);
          else {
            const size_t b = m / S_tok, s = m % S_tok;
            const size_t h = col >> 7, d = col & 127;
            out2[((b*HEADS + h)*HD + d) * S_tok + s] = __float2bfloat16(v);
          }
        } else {   // EPI 7: final residual, bf16 xin (out1) -> f32 out
          const float ev = mod[(m / S_tok) * 6 * DIM + (size_t)eidx * DIM + n];
          outf[m * N + n] = __bfloat162float(out1[m * N + n]) + v * ev;
        }
      }
}

// ---------------- flash attention: 32 q-rows/wave, V single-buf LDS, setprio + defer-max ----------------
__global__ __launch_bounds__(256, 2) void attn_fwd(
    const bf16* __restrict__ Q, const bf16* __restrict__ Kp, const bf16* __restrict__ Vt,
    bf16* __restrict__ O, int SQ, int SKV)
{
  const int tid = threadIdx.x, w = tid >> 6, l = tid & 63;
  const int lrow = l & 15, lhi = l >> 4;
  const int nwg = gridDim.x;
  const int p = blockIdx.x;
  const int f = (p & 7) * (nwg >> 3) + (p >> 3);
  const int nqb = SQ >> 7;
  const int xq = f % nqb;
  const int h  = (f / nqb) % HEADS;
  const int b  = f / (nqb * HEADS);
  const int q0 = xq * 128 + w * 32;

  __shared__ __align__(16) char kls[2][16384];
  __shared__ __align__(16) char vls[16384];
  __shared__ __align__(16) bf16 P[4][2][16][72];
  const float scale = 0.08838834764831845f;

  short8 qf[2][4];
  #pragma unroll
  for (int g = 0; g < 2; g++){
    const bf16* qp = Q + ((size_t)(b*SQ + q0 + g*16 + lrow))*DIM + h*HD + lhi*8;
    #pragma unroll
    for (int ds = 0; ds < 4; ds++) qf[g][ds] = *(const short8*)(qp + ds*32);
  }

  const bf16* kg = Kp + (size_t)b*SKV*DIM + h*HD;
  const bf16* vg = Vt + (size_t)(b*HEADS + h)*HD*SKV;

  f32x4 acc[2][8] = {};
  float m_run[2] = {-INFINITY, -INFINITY}, l_run[2] = {0.f, 0.f};
  const int nt = SKV >> 6;

  auto stage_k = [&](int buf, int kv0){
    char* kd = &kls[buf][0];
    #pragma unroll
    for (int i = 0; i < 4; i++){
      int sid = i*256 + tid;
      int row = sid >> 4, sg = sid & 15;
      int gsg = sg ^ (row & 7);
      gload_lds16(kg + (size_t)(kv0 + row)*DIM + gsg*8, kd + sid*16);
    }
  };
  auto stage_v = [&](int kv0){
    #pragma unroll
    for (int i = 0; i < 4; i++){
      int sid = i*256 + tid;
      int d = sid >> 3, sg = sid & 7;
      int gsg = sg ^ (d & 7);
      gload_lds16(vg + (size_t)d*SKV + kv0 + gsg*8, &vls[0] + sid*16);
    }
  };

  stage_k(0, 0);
  stage_v(0);
  asm volatile("s_waitcnt vmcnt(0)" ::: "memory");
  __builtin_amdgcn_s_barrier();

  for (int t = 0; t < nt; ++t){
    if (t > 0)      stage_v(t * 64);
    if (t + 1 < nt) stage_k((t + 1) & 1, (t + 1) * 64);
    const char* kb = &kls[t & 1][0];

    f32x4 st[2][4] = {};
    __builtin_amdgcn_s_setprio(1);
    #pragma unroll
    for (int kvf = 0; kvf < 4; kvf++){
      const int row = kvf*16 + lrow;
      const int rx = row & 7;
      #pragma unroll
      for (int ds = 0; ds < 4; ds++){
        const int seg = (ds*4 + lhi) ^ rx;
        short8 kf = *(const short8*)(kb + row*256 + seg*16);
        st[0][kvf] = mfma16(kf, qf[0][ds], st[0][kvf]);
        st[1][kvf] = mfma16(kf, qf[1][ds], st[1][kvf]);
      }
    }
    __builtin_amdgcn_s_setprio(0);

    #pragma unroll
    for (int g = 0; g < 2; g++){
      float sv[16]; float smax = -INFINITY;
      #pragma unroll
      for (int kvf = 0; kvf < 4; kvf++)
        #pragma unroll
        for (int r = 0; r < 4; r++){
          float xv = st[g][kvf][r] * scale;
          sv[kvf*4+r] = xv; smax = fmaxf(smax, xv);
        }
      smax = fmaxf(smax, __shfl_xor(smax, 16, 64));
      smax = fmaxf(smax, __shfl_xor(smax, 32, 64));
      const bool nore = __all(smax <= m_run[g] + 8.0f);
      const float mnew = nore ? m_run[g] : fmaxf(m_run[g], smax);
      float psum = 0.f;
      #pragma unroll
      for (int i = 0; i < 16; i++){ float pe = __expf(sv[i] - mnew); sv[i] = pe; psum += pe; }
      psum += __shfl_xor(psum, 16, 64); psum += __shfl_xor(psum, 32, 64);
      #pragma unroll
      for (int kvf = 0; kvf < 4; kvf++){
        short4v o;
        #pragma unroll
        for (int r = 0; r < 4; r++) o[r] = f2bs(sv[kvf*4+r]);
        *(short4v*)&P[w][g][lrow][kvf*16 + lhi*4] = o;
      }
      if (nore){
        l_run[g] += psum;
      } else {
        const float corr = __expf(m_run[g] - mnew);
        l_run[g] = l_run[g] * corr + psum;
        m_run[g] = mnew;
        float cr[4];
        #pragma unroll
        for (int r = 0; r < 4; r++) cr[r] = __shfl(corr, lhi*4 + r, 64);
        #pragma unroll
        for (int df = 0; df < 8; df++){
          acc[g][df][0] *= cr[0]; acc[g][df][1] *= cr[1];
          acc[g][df][2] *= cr[2]; acc[g][df][3] *= cr[3];
        }
      }
    }

    if (t + 1 < nt) { asm volatile("s_waitcnt vmcnt(4)" ::: "memory"); }
    else            { asm volatile("s_waitcnt vmcnt(0)" ::: "memory"); }
    __builtin_amdgcn_s_barrier();
    asm volatile("s_waitcnt lgkmcnt(0)" ::: "memory");
    __builtin_amdgcn_sched_barrier(0);

    short8 pf[2][2];
    #pragma unroll
    for (int g = 0; g < 2; g++){
      pf[g][0] = *(const short8*)&P[w][g][lrow][lhi*8];
      pf[g][1] = *(const short8*)&P[w][g][lrow][32 + lhi*8];
    }
    __builtin_amdgcn_s_setprio(1);
    #pragma unroll
    for (int df = 0; df < 8; df++){
      const int d = df*16 + lrow;
      const int dx = d & 7;
      short8 vf0 = *(const short8*)(&vls[0] + d*128 + ((lhi)     ^ dx)*16);
      short8 vf1 = *(const short8*)(&vls[0] + d*128 + ((lhi + 4) ^ dx)*16);
      acc[0][df] = mfma16(pf[0][0], vf0, acc[0][df]);
      acc[0][df] = mfma16(pf[0][1], vf1, acc[0][df]);
      acc[1][df] = mfma16(pf[1][0], vf0, acc[1][df]);
      acc[1][df] = mfma16(pf[1][1], vf1, acc[1][df]);
    }
    __builtin_amdgcn_s_setprio(0);
    if (t + 1 < nt) { asm volatile("s_waitcnt vmcnt(0)" ::: "memory"); }
    __builtin_amdgcn_s_barrier();
  }

  #pragma unroll
  for (int g = 0; g < 2; g++){
    const float linv = 1.0f / l_run[g];
    float li[4];
    #pragma unroll
    for (int r = 0; r < 4; r++) li[r] = __shfl(linv, lhi*4 + r, 64);
    #pragma unroll
    for (int df = 0; df < 8; df++)
      #pragma unroll
      for (int r = 0; r < 4; r++){
        const size_t q = q0 + g*16 + lhi*4 + r;
        O[((size_t)(b*SQ + q))*DIM + h*HD + df*16 + lrow] = __float2bfloat16(acc[g][df][r] * li[r]);
      }
  }
}

// ---------------- host ----------------

extern "C" void kernel_launch(void* const* d_in, const int* in_sizes, int n_in,
                              void* d_out, int out_size, void* d_ws, size_t ws_size,
                              hipStream_t stream)
{
  const float* x    = (const float*)d_in[0];
  const float* e    = (const float*)d_in[1];
  const float* ctx  = (const float*)d_in[2];
  const float* modw = (const float*)d_in[3];
  const float* n1w  = (const float*)d_in[4];
  const float* n2w  = (const float*)d_in[5];
  const float* n3w  = (const float*)d_in[6];
  const float* nqw  = (const float*)d_in[7];
  const float* nkw  = (const float*)d_in[8];
  const float* fnw  = (const float*)d_in[9];
  const float* saqw = (const float*)d_in[10]; const float* saqb = (const float*)d_in[11];
  const float* sakw = (const float*)d_in[12]; const float* sakb = (const float*)d_in[13];
  const float* savw = (const float*)d_in[14]; const float* savb = (const float*)d_in[15];
  const float* saow = (const float*)d_in[16]; const float* saob = (const float*)d_in[17];
  const float* caqw = (const float*)d_in[18]; const float* caqb = (const float*)d_in[19];
  const float* cakw = (const float*)d_in[20]; const float* cakb = (const float*)d_in[21];
  const float* cavw = (const float*)d_in[22]; const float* cavb = (const float*)d_in[23];
  const float* caow = (const float*)d_in[24]; const float* caob = (const float*)d_in[25];
  const float* fw1  = (const float*)d_in[26]; const float* fb1  = (const float*)d_in[27];
  const float* fw2  = (const float*)d_in[28]; const float* fb2  = (const float*)d_in[29];
  float* out = (float*)d_out;
  (void)in_sizes; (void)n_in; (void)out_size; (void)ws_size;

  char* ws = (char*)d_ws;
  size_t off = 0;
  auto alloc = [&](size_t bytes) -> void* {
    void* p = ws + off; off = (off + bytes + 255) & ~(size_t)255; return p;
  };
  bf16*  wt   = (bf16*)alloc((size_t)FFND * DIM * 2);
  float* mod  = (float*)alloc((size_t)BATCH * 6 * DIM * 4);
  float* bcat = (float*)alloc((size_t)3 * DIM * 4);
  float* bcat2= (float*)alloc((size_t)2 * DIM * 4);
  bf16*  ctxb = (bf16*)alloc((size_t)BATCH * CLEN * DIM * 2);
  bf16*  hbuf = (bf16*)alloc((size_t)BATCH * SEQ * DIM * 2);
  bf16*  qbuf = (bf16*)alloc((size_t)BATCH * SEQ * DIM * 2);
  bf16*  kbuf = (bf16*)alloc((size_t)BATCH * SEQ * DIM * 2);
  bf16*  vtb  = (bf16*)alloc((size_t)BATCH * SEQ * DIM * 2);
  bf16*  aout = (bf16*)alloc((size_t)BATCH * SEQ * DIM * 2);
  bf16*  xcurb= (bf16*)alloc((size_t)BATCH * SEQ * DIM * 2);
  bf16*  hf   = (bf16*)alloc((size_t)BATCH * SEQ * FFND * 2);

  const int M = BATCH * SEQ;     // 4096
  const int Mc = BATCH * CLEN;   // 1024

  modadd_k<<<dim3(96), dim3(256), 0, stream>>>(modw, e, mod);
  f2b8_k<<<dim3(1024), dim3(256), 0, stream>>>(ctx, ctxb);
  biascat_k<<<dim3(40), dim3(256), 0, stream>>>(saqb, sakb, savb, cakb, cavb, bcat, bcat2);

  // --- self attention: fused QKV (N=6144) ---
  norm_x<<<dim3(M), dim3(256), 0, stream>>>(x, n1w, mod, hbuf, SEQ);

  transpose_w3<<<dim3(DIM/64, DIM/64, 3), dim3(256), 0, stream>>>(saqw, sakw, savw, wt, DIM, DIM);
  gemm_bf16<5><<<dim3((3*DIM/256)*(M/128)), dim3(512), 0, stream>>>(hbuf, wt, bcat, nullptr, nullptr, nullptr, qbuf, kbuf, vtb, M, 3*DIM, DIM, SEQ, 0);
  rmsnorm2_bf16_ip<<<dim3(2*M), dim3(256), 0, stream>>>(qbuf, nqw, kbuf, nkw, M);

  attn_fwd<<<dim3((SEQ/128)*HEADS*BATCH), dim3(256), 0, stream>>>(qbuf, kbuf, vtb, aout, SEQ, SEQ);

  transpose_w<<<dim3(DIM/64, DIM/64), dim3(256), 0, stream>>>(saow, wt, DIM, DIM);
  gemm_bf16<2><<<dim3((DIM/256)*(M/128)), dim3(512), 0, stream>>>(aout, wt, saob, x, mod, nullptr, xcurb, nullptr, nullptr, M, DIM, DIM, SEQ, 2);

  // --- cross attention: q gemm + fused KV gemm (N=4096) ---
  norm_xb<2><<<dim3(M), dim3(256), 0, stream>>>(xcurb, n2w, nullptr, mod, hbuf, SEQ);

  transpose_w3<<<dim3(DIM/64, DIM/64, 3), dim3(256), 0, stream>>>(caqw, cakw, cavw, wt, DIM, DIM);
  gemm_bf16<0><<<dim3((DIM/256)*(M/128)), dim3(512), 0, stream>>>(hbuf, wt, caqb, nullptr, nullptr, nullptr, qbuf, nullptr, nullptr, M, DIM, DIM, SEQ, 0);
  gemm_bf16<6><<<dim3((2*DIM/256)*(Mc/128)), dim3(512), 0, stream>>>(ctxb, wt + (size_t)DIM*DIM, bcat2, nullptr, nullptr, nullptr, nullptr, kbuf, vtb, Mc, 2*DIM, DIM, CLEN, 0);

  attn_fwd<<<dim3((SEQ/128)*HEADS*BATCH), dim3(256), 0, stream>>>(qbuf, kbuf, vtb, aout, SEQ, CLEN);

  transpose_w<<<dim3(DIM/64, DIM/64), dim3(256), 0, stream>>>(caow, wt, DIM, DIM);
  gemm_bf16<3><<<dim3((DIM/256)*(M/128)), dim3(512), 0, stream>>>(aout, wt, caob, nullptr, nullptr, nullptr, xcurb, nullptr, nullptr, M, DIM, DIM, SEQ, 0);

  // --- FFN ---
  norm_xb<3><<<dim3(M), dim3(256), 0, stream>>>(xcurb, n3w, fnw, mod, hbuf, SEQ);

  transpose_w<<<dim3(FFND/64, DIM/64), dim3(256), 0, stream>>>(fw1, wt, DIM, FFND);
  gemm_bf16<4><<<dim3((FFND/256)*(M/128)), dim3(512), 0, stream>>>(hbuf, wt, fb1, nullptr, nullptr, nullptr, hf, nullptr, nullptr, M, FFND, DIM, SEQ, 0);

  transpose_w<<<dim3(DIM/64, FFND/64), dim3(256), 0, stream>>>(fw2, wt, FFND, DIM);
  gemm_bf16<7><<<dim3((DIM/256)*(M/128)), dim3(512), 0, stream>>>(hf, wt, fb2, nullptr, mod, out, nullptr, xcurb, nullptr, M, DIM, FFND, SEQ, 5);
}

// Round 22
// 869.051 us; speedup vs baseline: 1.0982x; 1.0069x over previous
//
#include <hip/hip_runtime.h>
#include <hip/hip_bf16.h>
#include <cstdint>

#define DIM   2048
#define HEADS 16
#define HD    128
#define SEQ   2048
#define CLEN  512
#define FFND  8192
#define BATCH 2

using bf16 = __hip_bfloat16;
typedef __attribute__((ext_vector_type(8))) short  short8;
typedef __attribute__((ext_vector_type(4))) short  short4v;
typedef __attribute__((ext_vector_type(4))) float  f32x4;
typedef __attribute__((ext_vector_type(8))) __bf16 bf16x8;

__device__ __forceinline__ short f2bs(float f){ bf16 h = __float2bfloat16(f); return __builtin_bit_cast(short, h); }
__device__ __forceinline__ float bs2f(short s){ return __builtin_bit_cast(float, (uint32_t)((uint16_t)s) << 16); }

__device__ __forceinline__ f32x4 mfma16(short8 a, short8 b, f32x4 c){
  return __builtin_amdgcn_mfma_f32_16x16x32_bf16(
      __builtin_bit_cast(bf16x8, a), __builtin_bit_cast(bf16x8, b), c, 0, 0, 0);
}

__device__ __forceinline__ void gload_lds16(const void* g, const void* l){
  __builtin_amdgcn_global_load_lds(
      (const __attribute__((address_space(1))) void*)(uintptr_t)g,
      (__attribute__((address_space(3))) void*)(uint32_t)(uintptr_t)l, 16, 0, 0);
}

__device__ __forceinline__ float block_sum(float v, float* sbuf, int tid){
  #pragma unroll
  for (int m = 32; m >= 1; m >>= 1) v += __shfl_xor(v, m, 64);
  const int w = tid >> 6;
  if ((tid & 63) == 0) sbuf[w] = v;
  __syncthreads();
  float r = sbuf[0] + sbuf[1] + sbuf[2] + sbuf[3];
  __syncthreads();
  return r;
}

// ---------------- merged prologue ----------------
// blocks [0,96):        mod = modw (broadcast) + e           (24576 f32)
// blocks [96,1120):     ctxb = bf16(ctx)                     (2M elems, 8/thread)
// blocks [1120,1160):   bcat = saqb||sakb||savb ; bcat2 = cakb||cavb
__global__ void prologue_k(const float* __restrict__ modw, const float* __restrict__ e,
                           float* __restrict__ mod,
                           const float* __restrict__ ctx, bf16* __restrict__ ctxb,
                           const float* __restrict__ b0, const float* __restrict__ b1,
                           const float* __restrict__ b2, const float* __restrict__ c0,
                           const float* __restrict__ c1, float* __restrict__ bcat,
                           float* __restrict__ bcat2){
  const int blk = blockIdx.x;
  if (blk < 96){
    int i = blk * 256 + threadIdx.x;
    mod[i] = modw[i % (6 * DIM)] + e[i];
  } else if (blk < 1120){
    int i = (blk - 96) * 256 + threadIdx.x;
    const float4* p = (const float4*)ctx;
    float4 a = p[2*i], c = p[2*i+1];
    short8 o;
    o[0]=f2bs(a.x); o[1]=f2bs(a.y); o[2]=f2bs(a.z); o[3]=f2bs(a.w);
    o[4]=f2bs(c.x); o[5]=f2bs(c.y); o[6]=f2bs(c.z); o[7]=f2bs(c.w);
    *((short8*)ctxb + i) = o;
  } else {
    int i = (blk - 1120) * 256 + threadIdx.x;
    if (i < 3*DIM){
      const float* src = (i < DIM) ? b0 : (i < 2*DIM) ? b1 : b2;
      bcat[i] = src[i & (DIM-1)];
    } else {
      int j = i - 3*DIM;
      const float* src = (j < DIM) ? c0 : c1;
      bcat2[j] = src[j & (DIM-1)];
    }
  }
}

// transpose + f32->bf16: W[K][N] -> Wt[N][K]; 64x64 tiles, short4 (8B) writes
__global__ __launch_bounds__(256) void transpose_w(const float* __restrict__ W,
                                                   bf16* __restrict__ Wt, int K, int N){
  __shared__ float tile[64][65];
  const int tx = threadIdx.x & 63, ty = threadIdx.x >> 6;
  const size_t k0 = (size_t)blockIdx.y * 64, n0 = (size_t)blockIdx.x * 64;
  #pragma unroll
  for (int i = 0; i < 16; i++)
    tile[ty + i*4][tx] = W[(k0 + ty + i*4) * (size_t)N + n0 + tx];
  __syncthreads();
  const int kx = threadIdx.x & 15;
  const int ny = threadIdx.x >> 4;
  #pragma unroll
  for (int i = 0; i < 4; i++){
    const int n = ny + i*16;
    short4v o;
    #pragma unroll
    for (int j = 0; j < 4; j++) o[j] = f2bs(tile[kx*4 + j][n]);
    *(short4v*)&Wt[(n0 + n) * (size_t)K + k0 + kx*4] = o;
  }
}

// 3 square transposes in one launch (blockIdx.z selects source; dst offset z*K*N)
__global__ __launch_bounds__(256) void transpose_w3(const float* __restrict__ W0,
    const float* __restrict__ W1, const float* __restrict__ W2,
    bf16* __restrict__ Wt, int K, int N){
  __shared__ float tile[64][65];
  const float* W = (blockIdx.z == 0) ? W0 : (blockIdx.z == 1) ? W1 : W2;
  bf16* dst = Wt + (size_t)blockIdx.z * K * N;
  const int tx = threadIdx.x & 63, ty = threadIdx.x >> 6;
  const size_t k0 = (size_t)blockIdx.y * 64, n0 = (size_t)blockIdx.x * 64;
  #pragma unroll
  for (int i = 0; i < 16; i++)
    tile[ty + i*4][tx] = W[(k0 + ty + i*4) * (size_t)N + n0 + tx];
  __syncthreads();
  const int kx = threadIdx.x & 15;
  const int ny = threadIdx.x >> 4;
  #pragma unroll
  for (int i = 0; i < 4; i++){
    const int n = ny + i*16;
    short4v o;
    #pragma unroll
    for (int j = 0; j < 4; j++) o[j] = f2bs(tile[kx*4 + j][n]);
    *(short4v*)&dst[(n0 + n) * (size_t)K + k0 + kx*4] = o;
  }
}

// MODE 1 only (f32 input x): out = bf16( rms(x)*w1*(1+e1) + e0 )
__global__ __launch_bounds__(256) void norm_x(const float* __restrict__ x,
    const float* __restrict__ w1, const float* __restrict__ mod,
    bf16* __restrict__ out, int S)
{
  const int row = blockIdx.x, tid = threadIdx.x;
  const int b = row / S;
  __shared__ float sbuf[4];
  const float* xr = x + (size_t)row * DIM;
  float v[8];
  #pragma unroll
  for (int i = 0; i < 2; i++){
    float4 t = *(const float4*)(xr + i*1024 + tid*4);
    v[i*4+0]=t.x; v[i*4+1]=t.y; v[i*4+2]=t.z; v[i*4+3]=t.w;
  }
  float ss = 0.f;
  #pragma unroll
  for (int j = 0; j < 8; j++) ss += v[j]*v[j];
  ss = block_sum(ss, sbuf, tid);
  const float r = rsqrtf(ss * (1.0f/DIM) + 1e-6f);
  const float* mb = mod + (size_t)b * 6 * DIM;
  #pragma unroll
  for (int i = 0; i < 2; i++){
    short4v o;
    #pragma unroll
    for (int j = 0; j < 4; j++){
      int n = i*1024 + tid*4 + j;
      float val = v[i*4+j] * r * w1[n];
      val = val * (1.f + mb[DIM + n]) + mb[n];
      o[j] = f2bs(val);
    }
    *(short4v*)(out + (size_t)row*DIM + i*1024 + tid*4) = o;
  }
}

// bf16-input norms (residual stream in bf16):
// MODE 2: out = bf16( rms(x)*w1 )
// MODE 3: t = rms_a(x)*w1*(1+e4)+e3 ; out = bf16( rms_b(t)*w2 )
template<int MODE>
__global__ __launch_bounds__(256) void norm_xb(const bf16* __restrict__ x,
    const float* __restrict__ w1, const float* __restrict__ w2,
    const float* __restrict__ mod, bf16* __restrict__ out, int S)
{
  const int row = blockIdx.x, tid = threadIdx.x;
  const int b = row / S;
  __shared__ float sbuf[4];
  const bf16* xr = x + (size_t)row * DIM;
  short8 vv = *(const short8*)(xr + tid*8);
  float v[8]; float ss = 0.f;
  #pragma unroll
  for (int j = 0; j < 8; j++){ v[j] = bs2f(vv[j]); ss += v[j]*v[j]; }
  ss = block_sum(ss, sbuf, tid);
  const float r = rsqrtf(ss * (1.0f/DIM) + 1e-6f);
  const float* mb = mod + (size_t)b * 6 * DIM;
  float t8[8];
  #pragma unroll
  for (int j = 0; j < 8; j++){
    int n = tid*8 + j;
    float val = v[j] * r * w1[n];
    if (MODE == 3) val = val * (1.f + mb[4*DIM + n]) + mb[3*DIM + n];
    t8[j] = val;
  }
  if (MODE == 3){
    float s2 = 0.f;
    #pragma unroll
    for (int j = 0; j < 8; j++) s2 += t8[j]*t8[j];
    s2 = block_sum(s2, sbuf, tid);
    const float r2 = rsqrtf(s2 * (1.0f/DIM) + 1e-6f);
    #pragma unroll
    for (int j = 0; j < 8; j++) t8[j] = t8[j] * r2 * w2[tid*8 + j];
  }
  short8 o;
  #pragma unroll
  for (int j = 0; j < 8; j++) o[j] = f2bs(t8[j]);
  *(short8*)(out + (size_t)row*DIM + tid*8) = o;
}

// in-place rmsnorm on bf16 rows: rows [0,M) -> xq with wq, rows [M,2M) -> xk with wk
__global__ __launch_bounds__(256) void rmsnorm2_bf16_ip(bf16* __restrict__ xq, const float* __restrict__ wq,
                                                        bf16* __restrict__ xk, const float* __restrict__ wk,
                                                        int M){
  const int row = blockIdx.x, tid = threadIdx.x;
  __shared__ float sbuf[4];
  bf16* xr; const float* w;
  if (row < M){ xr = xq + (size_t)row * DIM; w = wq; }
  else        { xr = xk + (size_t)(row - M) * DIM; w = wk; }
  short8 v = *(const short8*)(xr + tid*8);
  float f[8]; float ss = 0.f;
  #pragma unroll
  for (int j = 0; j < 8; j++){ f[j] = bs2f(v[j]); ss += f[j]*f[j]; }
  ss = block_sum(ss, sbuf, tid);
  const float r = rsqrtf(ss * (1.0f/DIM) + 1e-6f);
  short8 o;
  #pragma unroll
  for (int j = 0; j < 8; j++) o[j] = f2bs(f[j] * r * w[tid*8 + j]);
  *(short8*)(xr + tid*8) = o;
}

// ---------------- GEMM (champion): BM=128, BN=256, BK=32 ----------------
// 512 threads = 8 waves (2M x 4N), per-wave 64x64. Triple-buffered LDS,
// counted vmcnt(3), seg-XOR swizzle (0 conflicts), setprio, T1 n-major chunk.
// EPI 0: outb=bf16(v)                 1: Vt layout
// EPI 2: outb = bf16(xin[f32] + v*mod[eidx])
// EPI 3: outb = bf16(bf2f(outb) + v)
// EPI 4: gelu->outb                   5: QKV split (N=6144)
// EPI 6: KV split (N=4096)            7: outf = bf2f(out1) + v*mod[eidx]
#define GBUF 24576
template<int EPI>
__global__ __launch_bounds__(512, 2) void gemm_bf16(
    const bf16* __restrict__ A, const bf16* __restrict__ Bt,
    const float* __restrict__ bias, const float* __restrict__ xin,
    const float* __restrict__ mod, float* __restrict__ outf,
    bf16* __restrict__ outb, bf16* __restrict__ out1, bf16* __restrict__ out2,
    int M, int N, int K, int S_tok, int eidx)
{
  __shared__ __align__(16) char lds[3][GBUF];
  const int tid = threadIdx.x;
  const int w = tid >> 6, l = tid & 63;
  const int lrow = l & 15, lhi = l >> 4;
  const int wm = w >> 2, wn = w & 3;
  const int My = M >> 7;
  const int nwg = (N >> 8) * My;
  const int p = (int)blockIdx.x;
  const int fz = (p & 7) * (nwg >> 3) + (p >> 3);
  const size_t m0 = (size_t)(fz % My) * 128;
  const size_t n0 = (size_t)(fz / My) * 256;

  f32x4 acc[4][4] = {};

  auto gofs = [&](int sid){ return (size_t)(sid >> 2) * K + (size_t)(((sid & 3) ^ ((sid >> 3) & 3)) * 8); };
  const bf16* gA0 = A  + m0 * K + gofs(tid);
  const bf16* gB0 = Bt + n0 * K + gofs(tid);
  const bf16* gB1 = Bt + n0 * K + gofs(tid + 512);

  auto stage = [&](int kt, char* buf){
    const size_t ko = (size_t)kt * 32;
    gload_lds16(gA0 + ko, buf + tid * 16);
    gload_lds16(gB0 + ko, buf + 8192 + tid * 16);
    gload_lds16(gB1 + ko, buf + 8192 + (tid + 512) * 16);
  };

  const int nt = K >> 5;
  stage(0, lds[0]);
  stage(1, lds[1]);
  asm volatile("s_waitcnt vmcnt(3)" ::: "memory");
  __builtin_amdgcn_s_barrier();
  __builtin_amdgcn_sched_barrier(0);

  const int sread = (lhi ^ ((lrow >> 1) & 3)) * 16;

  int bi = 0;
  for (int t = 0; t < nt; ++t){
    const char* br = lds[bi];
    const bool st = (t + 2 < nt);
    if (st){
      int wi = bi + 2; if (wi >= 3) wi -= 3;
      stage(t + 2, lds[wi]);
    }
    short8 af[4], bf[4];
    #pragma unroll
    for (int mi = 0; mi < 4; mi++)
      af[mi] = *(const short8*)(br + (wm*64 + mi*16 + lrow)*64 + sread);
    #pragma unroll
    for (int ni = 0; ni < 4; ni++)
      bf[ni] = *(const short8*)(br + 8192 + (wn*64 + ni*16 + lrow)*64 + sread);
    __builtin_amdgcn_s_setprio(1);
    #pragma unroll
    for (int mi = 0; mi < 4; mi++)
      #pragma unroll
      for (int ni = 0; ni < 4; ni++)
        acc[mi][ni] = mfma16(af[mi], bf[ni], acc[mi][ni]);
    __builtin_amdgcn_s_setprio(0);
    if (st)               { asm volatile("s_waitcnt vmcnt(3)" ::: "memory"); }
    else if (t + 1 < nt)  { asm volatile("s_waitcnt vmcnt(0)" ::: "memory"); }
    __builtin_amdgcn_s_barrier();
    __builtin_amdgcn_sched_barrier(0);
    bi = (bi + 1 == 3) ? 0 : bi + 1;
  }

  #pragma unroll
  for (int mi = 0; mi < 4; mi++)
    #pragma unroll
    for (int ni = 0; ni < 4; ni++)
      #pragma unroll
      for (int r = 0; r < 4; r++){
        const size_t m = m0 + wm*64 + mi*16 + lhi*4 + r;
        const size_t n = n0 + wn*64 + ni*16 + lrow;
        float v = acc[mi][ni][r] + bias[n];
        if constexpr (EPI == 0) {
          outb[m * N + n] = __float2bfloat16(v);
        } else if constexpr (EPI == 1) {
          const size_t b = m / S_tok, s = m % S_tok;
          const size_t h = n >> 7, d = n & 127;
          outb[((b*HEADS + h)*HD + d) * S_tok + s] = __float2bfloat16(v);
        } else if constexpr (EPI == 2) {
          const float ev = mod[(m / S_tok) * 6 * DIM + (size_t)eidx * DIM + n];
          outb[m * N + n] = __float2bfloat16(xin[m * N + n] + v * ev);
        } else if constexpr (EPI == 3) {
          const float xv = __bfloat162float(outb[m * N + n]);
          outb[m * N + n] = __float2bfloat16(xv + v);
        } else if constexpr (EPI == 4) {
          float u = 0.7978845608028654f * (v + 0.044715f * v * v * v);
          outb[m * N + n] = __float2bfloat16(0.5f * v * (1.0f + tanhf(u)));
        } else if constexpr (EPI == 5) {   // QKV split (N = 6144)
          const size_t sg = n >> 11, col = n & 2047;
          if (sg == 0)      outb[m * DIM + col] = __float2bfloat16(v);
          else if (sg == 1) out1[m * DIM + col] = __float2bfloat16(v);
          else {
            const size_t b = m / S_tok, s = m % S_tok;
            const size_t h = col >> 7, d = col & 127;
            out2[((b*HEADS + h)*HD + d) * S_tok + s] = __float2bfloat16(v);
          }
        } else if constexpr (EPI == 6) {   // KV split (N = 4096)
          const size_t sg = n >> 11, col = n & 2047;
          if (sg == 0) out1[m * DIM + col] = __float2bfloat16(v);
          else {
            const size_t b = m / S_tok, s = m % S_tok;
            const size_t h = col >> 7, d = col & 127;
            out2[((b*HEADS + h)*HD + d) * S_tok + s] = __float2bfloat16(v);
          }
        } else {   // EPI 7: final residual, bf16 xin (out1) -> f32 out
          const float ev = mod[(m / S_tok) * 6 * DIM + (size_t)eidx * DIM + n];
          outf[m * N + n] = __bfloat162float(out1[m * N + n]) + v * ev;
        }
      }
}

// ---------------- flash attention: 32 q-rows/wave, V single-buf LDS, setprio + defer-max ----------------
__global__ __launch_bounds__(256, 2) void attn_fwd(
    const bf16* __restrict__ Q, const bf16* __restrict__ Kp, const bf16* __restrict__ Vt,
    bf16* __restrict__ O, int SQ, int SKV)
{
  const int tid = threadIdx.x, w = tid >> 6, l = tid & 63;
  const int lrow = l & 15, lhi = l >> 4;
  const int nwg = gridDim.x;
  const int p = blockIdx.x;
  const int f = (p & 7) * (nwg >> 3) + (p >> 3);
  const int nqb = SQ >> 7;
  const int xq = f % nqb;
  const int h  = (f / nqb) % HEADS;
  const int b  = f / (nqb * HEADS);
  const int q0 = xq * 128 + w * 32;

  __shared__ __align__(16) char kls[2][16384];
  __shared__ __align__(16) char vls[16384];
  __shared__ __align__(16) bf16 P[4][2][16][72];
  const float scale = 0.08838834764831845f;

  short8 qf[2][4];
  #pragma unroll
  for (int g = 0; g < 2; g++){
    const bf16* qp = Q + ((size_t)(b*SQ + q0 + g*16 + lrow))*DIM + h*HD + lhi*8;
    #pragma unroll
    for (int ds = 0; ds < 4; ds++) qf[g][ds] = *(const short8*)(qp + ds*32);
  }

  const bf16* kg = Kp + (size_t)b*SKV*DIM + h*HD;
  const bf16* vg = Vt + (size_t)(b*HEADS + h)*HD*SKV;

  f32x4 acc[2][8] = {};
  float m_run[2] = {-INFINITY, -INFINITY}, l_run[2] = {0.f, 0.f};
  const int nt = SKV >> 6;

  auto stage_k = [&](int buf, int kv0){
    char* kd = &kls[buf][0];
    #pragma unroll
    for (int i = 0; i < 4; i++){
      int sid = i*256 + tid;
      int row = sid >> 4, sg = sid & 15;
      int gsg = sg ^ (row & 7);
      gload_lds16(kg + (size_t)(kv0 + row)*DIM + gsg*8, kd + sid*16);
    }
  };
  auto stage_v = [&](int kv0){
    #pragma unroll
    for (int i = 0; i < 4; i++){
      int sid = i*256 + tid;
      int d = sid >> 3, sg = sid & 7;
      int gsg = sg ^ (d & 7);
      gload_lds16(vg + (size_t)d*SKV + kv0 + gsg*8, &vls[0] + sid*16);
    }
  };

  stage_k(0, 0);
  stage_v(0);
  asm volatile("s_waitcnt vmcnt(0)" ::: "memory");
  __builtin_amdgcn_s_barrier();

  for (int t = 0; t < nt; ++t){
    if (t > 0)      stage_v(t * 64);
    if (t + 1 < nt) stage_k((t + 1) & 1, (t + 1) * 64);
    const char* kb = &kls[t & 1][0];

    f32x4 st[2][4] = {};
    __builtin_amdgcn_s_setprio(1);
    #pragma unroll
    for (int kvf = 0; kvf < 4; kvf++){
      const int row = kvf*16 + lrow;
      const int rx = row & 7;
      #pragma unroll
      for (int ds = 0; ds < 4; ds++){
        const int seg = (ds*4 + lhi) ^ rx;
        short8 kf = *(const short8*)(kb + row*256 + seg*16);
        st[0][kvf] = mfma16(kf, qf[0][ds], st[0][kvf]);
        st[1][kvf] = mfma16(kf, qf[1][ds], st[1][kvf]);
      }
    }
    __builtin_amdgcn_s_setprio(0);

    #pragma unroll
    for (int g = 0; g < 2; g++){
      float sv[16]; float smax = -INFINITY;
      #pragma unroll
      for (int kvf = 0; kvf < 4; kvf++)
        #pragma unroll
        for (int r = 0; r < 4; r++){
          float xv = st[g][kvf][r] * scale;
          sv[kvf*4+r] = xv; smax = fmaxf(smax, xv);
        }
      smax = fmaxf(smax, __shfl_xor(smax, 16, 64));
      smax = fmaxf(smax, __shfl_xor(smax, 32, 64));
      const bool nore = __all(smax <= m_run[g] + 8.0f);
      const float mnew = nore ? m_run[g] : fmaxf(m_run[g], smax);
      float psum = 0.f;
      #pragma unroll
      for (int i = 0; i < 16; i++){ float pe = __expf(sv[i] - mnew); sv[i] = pe; psum += pe; }
      psum += __shfl_xor(psum, 16, 64); psum += __shfl_xor(psum, 32, 64);
      #pragma unroll
      for (int kvf = 0; kvf < 4; kvf++){
        short4v o;
        #pragma unroll
        for (int r = 0; r < 4; r++) o[r] = f2bs(sv[kvf*4+r]);
        *(short4v*)&P[w][g][lrow][kvf*16 + lhi*4] = o;
      }
      if (nore){
        l_run[g] += psum;
      } else {
        const float corr = __expf(m_run[g] - mnew);
        l_run[g] = l_run[g] * corr + psum;
        m_run[g] = mnew;
        float cr[4];
        #pragma unroll
        for (int r = 0; r < 4; r++) cr[r] = __shfl(corr, lhi*4 + r, 64);
        #pragma unroll
        for (int df = 0; df < 8; df++){
          acc[g][df][0] *= cr[0]; acc[g][df][1] *= cr[1];
          acc[g][df][2] *= cr[2]; acc[g][df][3] *= cr[3];
        }
      }
    }

    if (t + 1 < nt) { asm volatile("s_waitcnt vmcnt(4)" ::: "memory"); }
    else            { asm volatile("s_waitcnt vmcnt(0)" ::: "memory"); }
    __builtin_amdgcn_s_barrier();
    asm volatile("s_waitcnt lgkmcnt(0)" ::: "memory");
    __builtin_amdgcn_sched_barrier(0);

    short8 pf[2][2];
    #pragma unroll
    for (int g = 0; g < 2; g++){
      pf[g][0] = *(const short8*)&P[w][g][lrow][lhi*8];
      pf[g][1] = *(const short8*)&P[w][g][lrow][32 + lhi*8];
    }
    __builtin_amdgcn_s_setprio(1);
    #pragma unroll
    for (int df = 0; df < 8; df++){
      const int d = df*16 + lrow;
      const int dx = d & 7;
      short8 vf0 = *(const short8*)(&vls[0] + d*128 + ((lhi)     ^ dx)*16);
      short8 vf1 = *(const short8*)(&vls[0] + d*128 + ((lhi + 4) ^ dx)*16);
      acc[0][df] = mfma16(pf[0][0], vf0, acc[0][df]);
      acc[0][df] = mfma16(pf[0][1], vf1, acc[0][df]);
      acc[1][df] = mfma16(pf[1][0], vf0, acc[1][df]);
      acc[1][df] = mfma16(pf[1][1], vf1, acc[1][df]);
    }
    __builtin_amdgcn_s_setprio(0);
    if (t + 1 < nt) { asm volatile("s_waitcnt vmcnt(0)" ::: "memory"); }
    __builtin_amdgcn_s_barrier();
  }

  #pragma unroll
  for (int g = 0; g < 2; g++){
    const float linv = 1.0f / l_run[g];
    float li[4];
    #pragma unroll
    for (int r = 0; r < 4; r++) li[r] = __shfl(linv, lhi*4 + r, 64);
    #pragma unroll
    for (int df = 0; df < 8; df++)
      #pragma unroll
      for (int r = 0; r < 4; r++){
        const size_t q = q0 + g*16 + lhi*4 + r;
        O[((size_t)(b*SQ + q))*DIM + h*HD + df*16 + lrow] = __float2bfloat16(acc[g][df][r] * li[r]);
      }
  }
}

// ---------------- host ----------------

extern "C" void kernel_launch(void* const* d_in, const int* in_sizes, int n_in,
                              void* d_out, int out_size, void* d_ws, size_t ws_size,
                              hipStream_t stream)
{
  const float* x    = (const float*)d_in[0];
  const float* e    = (const float*)d_in[1];
  const float* ctx  = (const float*)d_in[2];
  const float* modw = (const float*)d_in[3];
  const float* n1w  = (const float*)d_in[4];
  const float* n2w  = (const float*)d_in[5];
  const float* n3w  = (const float*)d_in[6];
  const float* nqw  = (const float*)d_in[7];
  const float* nkw  = (const float*)d_in[8];
  const float* fnw  = (const float*)d_in[9];
  const float* saqw = (const float*)d_in[10]; const float* saqb = (const float*)d_in[11];
  const float* sakw = (const float*)d_in[12]; const float* sakb = (const float*)d_in[13];
  const float* savw = (const float*)d_in[14]; const float* savb = (const float*)d_in[15];
  const float* saow = (const float*)d_in[16]; const float* saob = (const float*)d_in[17];
  const float* caqw = (const float*)d_in[18]; const float* caqb = (const float*)d_in[19];
  const float* cakw = (const float*)d_in[20]; const float* cakb = (const float*)d_in[21];
  const float* cavw = (const float*)d_in[22]; const float* cavb = (const float*)d_in[23];
  const float* caow = (const float*)d_in[24]; const float* caob = (const float*)d_in[25];
  const float* fw1  = (const float*)d_in[26]; const float* fb1  = (const float*)d_in[27];
  const float* fw2  = (const float*)d_in[28]; const float* fb2  = (const float*)d_in[29];
  float* out = (float*)d_out;
  (void)in_sizes; (void)n_in; (void)out_size; (void)ws_size;

  char* ws = (char*)d_ws;
  size_t off = 0;
  auto alloc = [&](size_t bytes) -> void* {
    void* p = ws + off; off = (off + bytes + 255) & ~(size_t)255; return p;
  };
  bf16*  wt   = (bf16*)alloc((size_t)FFND * DIM * 2);
  float* mod  = (float*)alloc((size_t)BATCH * 6 * DIM * 4);
  float* bcat = (float*)alloc((size_t)3 * DIM * 4);
  float* bcat2= (float*)alloc((size_t)2 * DIM * 4);
  bf16*  ctxb = (bf16*)alloc((size_t)BATCH * CLEN * DIM * 2);
  bf16*  hbuf = (bf16*)alloc((size_t)BATCH * SEQ * DIM * 2);
  bf16*  qbuf = (bf16*)alloc((size_t)BATCH * SEQ * DIM * 2);
  bf16*  kbuf = (bf16*)alloc((size_t)BATCH * SEQ * DIM * 2);
  bf16*  vtb  = (bf16*)alloc((size_t)BATCH * SEQ * DIM * 2);
  bf16*  aout = (bf16*)alloc((size_t)BATCH * SEQ * DIM * 2);
  bf16*  xcurb= (bf16*)alloc((size_t)BATCH * SEQ * DIM * 2);
  bf16*  hf   = (bf16*)alloc((size_t)BATCH * SEQ * FFND * 2);

  const int M = BATCH * SEQ;     // 4096
  const int Mc = BATCH * CLEN;   // 1024

  prologue_k<<<dim3(1160), dim3(256), 0, stream>>>(modw, e, mod, ctx, ctxb,
                                                   saqb, sakb, savb, cakb, cavb, bcat, bcat2);

  // --- self attention: fused QKV (N=6144) ---
  norm_x<<<dim3(M), dim3(256), 0, stream>>>(x, n1w, mod, hbuf, SEQ);

  transpose_w3<<<dim3(DIM/64, DIM/64, 3), dim3(256), 0, stream>>>(saqw, sakw, savw, wt, DIM, DIM);
  gemm_bf16<5><<<dim3((3*DIM/256)*(M/128)), dim3(512), 0, stream>>>(hbuf, wt, bcat, nullptr, nullptr, nullptr, qbuf, kbuf, vtb, M, 3*DIM, DIM, SEQ, 0);
  rmsnorm2_bf16_ip<<<dim3(2*M), dim3(256), 0, stream>>>(qbuf, nqw, kbuf, nkw, M);

  attn_fwd<<<dim3((SEQ/128)*HEADS*BATCH), dim3(256), 0, stream>>>(qbuf, kbuf, vtb, aout, SEQ, SEQ);

  transpose_w<<<dim3(DIM/64, DIM/64), dim3(256), 0, stream>>>(saow, wt, DIM, DIM);
  gemm_bf16<2><<<dim3((DIM/256)*(M/128)), dim3(512), 0, stream>>>(aout, wt, saob, x, mod, nullptr, xcurb, nullptr, nullptr, M, DIM, DIM, SEQ, 2);

  // --- cross attention: q gemm + fused KV gemm (N=4096) ---
  norm_xb<2><<<dim3(M), dim3(256), 0, stream>>>(xcurb, n2w, nullptr, mod, hbuf, SEQ);

  transpose_w3<<<dim3(DIM/64, DIM/64, 3), dim3(256), 0, stream>>>(caqw, cakw, cavw, wt, DIM, DIM);
  gemm_bf16<0><<<dim3((DIM/256)*(M/128)), dim3(512), 0, stream>>>(hbuf, wt, caqb, nullptr, nullptr, nullptr, qbuf, nullptr, nullptr, M, DIM, DIM, SEQ, 0);
  gemm_bf16<6><<<dim3((2*DIM/256)*(Mc/128)), dim3(512), 0, stream>>>(ctxb, wt + (size_t)DIM*DIM, bcat2, nullptr, nullptr, nullptr, nullptr, kbuf, vtb, Mc, 2*DIM, DIM, CLEN, 0);

  attn_fwd<<<dim3((SEQ/128)*HEADS*BATCH), dim3(256), 0, stream>>>(qbuf, kbuf, vtb, aout, SEQ, CLEN);

  transpose_w<<<dim3(DIM/64, DIM/64), dim3(256), 0, stream>>>(caow, wt, DIM, DIM);
  gemm_bf16<3><<<dim3((DIM/256)*(M/128)), dim3(512), 0, stream>>>(aout, wt, caob, nullptr, nullptr, nullptr, xcurb, nullptr, nullptr, M, DIM, DIM, SEQ, 0);

  // --- FFN ---
  norm_xb<3><<<dim3(M), dim3(256), 0, stream>>>(xcurb, n3w, fnw, mod, hbuf, SEQ);

  transpose_w<<<dim3(FFND/64, DIM/64), dim3(256), 0, stream>>>(fw1, wt, DIM, FFND);
  gemm_bf16<4><<<dim3((FFND/256)*(M/128)), dim3(512), 0, stream>>>(hbuf, wt, fb1, nullptr, nullptr, nullptr, hf, nullptr, nullptr, M, FFND, DIM, SEQ, 0);

  transpose_w<<<dim3(DIM/64, FFND/64), dim3(256), 0, stream>>>(fw2, wt, FFND, DIM);
  gemm_bf16<7><<<dim3((DIM/256)*(M/128)), dim3(512), 0, stream>>>(hf, wt, fb2, nullptr, mod, out, nullptr, xcurb, nullptr, M, DIM, FFND, SEQ, 5);
}

// Round 23
// 868.613 us; speedup vs baseline: 1.0988x; 1.0005x over previous
//
#include <hip/hip_runtime.h>
#include <hip/hip_bf16.h>
#include <cstdint>

#define DIM   2048
#define HEADS 16
#define HD    128
#define SEQ   2048
#define CLEN  512
#define FFND  8192
#define BATCH 2

using bf16 = __hip_bfloat16;
typedef __attribute__((ext_vector_type(8))) short  short8;
typedef __attribute__((ext_vector_type(4))) short  short4v;
typedef __attribute__((ext_vector_type(4))) float  f32x4;
typedef __attribute__((ext_vector_type(8))) __bf16 bf16x8;

__device__ __forceinline__ short f2bs(float f){ bf16 h = __float2bfloat16(f); return __builtin_bit_cast(short, h); }
__device__ __forceinline__ float bs2f(short s){ return __builtin_bit_cast(float, (uint32_t)((uint16_t)s) << 16); }

__device__ __forceinline__ f32x4 mfma16(short8 a, short8 b, f32x4 c){
  return __builtin_amdgcn_mfma_f32_16x16x32_bf16(
      __builtin_bit_cast(bf16x8, a), __builtin_bit_cast(bf16x8, b), c, 0, 0, 0);
}

__device__ __forceinline__ void gload_lds16(const void* g, const void* l){
  __builtin_amdgcn_global_load_lds(
      (const __attribute__((address_space(1))) void*)(uintptr_t)g,
      (__attribute__((address_space(3))) void*)(uint32_t)(uintptr_t)l, 16, 0, 0);
}

__device__ __forceinline__ float block_sum(float v, float* sbuf, int tid){
  #pragma unroll
  for (int m = 32; m >= 1; m >>= 1) v += __shfl_xor(v, m, 64);
  const int w = tid >> 6;
  if ((tid & 63) == 0) sbuf[w] = v;
  __syncthreads();
  float r = sbuf[0] + sbuf[1] + sbuf[2] + sbuf[3];
  __syncthreads();
  return r;
}

// ---------------- merged prologue ----------------
// blocks [0,96):        mod = modw (broadcast) + e           (24576 f32)
// blocks [96,1120):     ctxb = bf16(ctx)                     (2M elems, 8/thread)
// blocks [1120,1160):   bcat = saqb||sakb||savb ; bcat2 = cakb||cavb
__global__ void prologue_k(const float* __restrict__ modw, const float* __restrict__ e,
                           float* __restrict__ mod,
                           const float* __restrict__ ctx, bf16* __restrict__ ctxb,
                           const float* __restrict__ b0, const float* __restrict__ b1,
                           const float* __restrict__ b2, const float* __restrict__ c0,
                           const float* __restrict__ c1, float* __restrict__ bcat,
                           float* __restrict__ bcat2){
  const int blk = blockIdx.x;
  if (blk < 96){
    int i = blk * 256 + threadIdx.x;
    mod[i] = modw[i % (6 * DIM)] + e[i];
  } else if (blk < 1120){
    int i = (blk - 96) * 256 + threadIdx.x;
    const float4* p = (const float4*)ctx;
    float4 a = p[2*i], c = p[2*i+1];
    short8 o;
    o[0]=f2bs(a.x); o[1]=f2bs(a.y); o[2]=f2bs(a.z); o[3]=f2bs(a.w);
    o[4]=f2bs(c.x); o[5]=f2bs(c.y); o[6]=f2bs(c.z); o[7]=f2bs(c.w);
    *((short8*)ctxb + i) = o;
  } else {
    int i = (blk - 1120) * 256 + threadIdx.x;
    if (i < 3*DIM){
      const float* src = (i < DIM) ? b0 : (i < 2*DIM) ? b1 : b2;
      bcat[i] = src[i & (DIM-1)];
    } else {
      int j = i - 3*DIM;
      const float* src = (j < DIM) ? c0 : c1;
      bcat2[j] = src[j & (DIM-1)];
    }
  }
}

// transpose + f32->bf16: W[K][N] -> Wt[N][K]; 64x64 tiles,
// float4 (16B) loads + short4 (8B) writes, 65-pad LDS (2-way = free)
__global__ __launch_bounds__(256) void transpose_w(const float* __restrict__ W,
                                                   bf16* __restrict__ Wt, int K, int N){
  __shared__ float tile[64][65];
  const size_t k0 = (size_t)blockIdx.y * 64, n0 = (size_t)blockIdx.x * 64;
  const int c4 = threadIdx.x & 15;        // float4 column (0..15)
  const int r0 = threadIdx.x >> 4;        // row base (0..15)
  #pragma unroll
  for (int i = 0; i < 4; i++){
    const int r = r0 + i*16;
    float4 v = *(const float4*)&W[(k0 + r) * (size_t)N + n0 + c4*4];
    tile[r][c4*4+0] = v.x; tile[r][c4*4+1] = v.y;
    tile[r][c4*4+2] = v.z; tile[r][c4*4+3] = v.w;
  }
  __syncthreads();
  const int kx = threadIdx.x & 15;
  const int ny = threadIdx.x >> 4;
  #pragma unroll
  for (int i = 0; i < 4; i++){
    const int n = ny + i*16;
    short4v o;
    #pragma unroll
    for (int j = 0; j < 4; j++) o[j] = f2bs(tile[kx*4 + j][n]);
    *(short4v*)&Wt[(n0 + n) * (size_t)K + k0 + kx*4] = o;
  }
}

// 3 square transposes in one launch (blockIdx.z selects source; dst offset z*K*N)
__global__ __launch_bounds__(256) void transpose_w3(const float* __restrict__ W0,
    const float* __restrict__ W1, const float* __restrict__ W2,
    bf16* __restrict__ Wt, int K, int N){
  __shared__ float tile[64][65];
  const float* W = (blockIdx.z == 0) ? W0 : (blockIdx.z == 1) ? W1 : W2;
  bf16* dst = Wt + (size_t)blockIdx.z * K * N;
  const size_t k0 = (size_t)blockIdx.y * 64, n0 = (size_t)blockIdx.x * 64;
  const int c4 = threadIdx.x & 15;
  const int r0 = threadIdx.x >> 4;
  #pragma unroll
  for (int i = 0; i < 4; i++){
    const int r = r0 + i*16;
    float4 v = *(const float4*)&W[(k0 + r) * (size_t)N + n0 + c4*4];
    tile[r][c4*4+0] = v.x; tile[r][c4*4+1] = v.y;
    tile[r][c4*4+2] = v.z; tile[r][c4*4+3] = v.w;
  }
  __syncthreads();
  const int kx = threadIdx.x & 15;
  const int ny = threadIdx.x >> 4;
  #pragma unroll
  for (int i = 0; i < 4; i++){
    const int n = ny + i*16;
    short4v o;
    #pragma unroll
    for (int j = 0; j < 4; j++) o[j] = f2bs(tile[kx*4 + j][n]);
    *(short4v*)&dst[(n0 + n) * (size_t)K + k0 + kx*4] = o;
  }
}

// MODE 1 only (f32 input x): out = bf16( rms(x)*w1*(1+e1) + e0 )
__global__ __launch_bounds__(256) void norm_x(const float* __restrict__ x,
    const float* __restrict__ w1, const float* __restrict__ mod,
    bf16* __restrict__ out, int S)
{
  const int row = blockIdx.x, tid = threadIdx.x;
  const int b = row / S;
  __shared__ float sbuf[4];
  const float* xr = x + (size_t)row * DIM;
  float v[8];
  #pragma unroll
  for (int i = 0; i < 2; i++){
    float4 t = *(const float4*)(xr + i*1024 + tid*4);
    v[i*4+0]=t.x; v[i*4+1]=t.y; v[i*4+2]=t.z; v[i*4+3]=t.w;
  }
  float ss = 0.f;
  #pragma unroll
  for (int j = 0; j < 8; j++) ss += v[j]*v[j];
  ss = block_sum(ss, sbuf, tid);
  const float r = rsqrtf(ss * (1.0f/DIM) + 1e-6f);
  const float* mb = mod + (size_t)b * 6 * DIM;
  #pragma unroll
  for (int i = 0; i < 2; i++){
    short4v o;
    #pragma unroll
    for (int j = 0; j < 4; j++){
      int n = i*1024 + tid*4 + j;
      float val = v[i*4+j] * r * w1[n];
      val = val * (1.f + mb[DIM + n]) + mb[n];
      o[j] = f2bs(val);
    }
    *(short4v*)(out + (size_t)row*DIM + i*1024 + tid*4) = o;
  }
}

// bf16-input norms (residual stream in bf16):
// MODE 2: out = bf16( rms(x)*w1 )
// MODE 3: t = rms_a(x)*w1*(1+e4)+e3 ; out = bf16( rms_b(t)*w2 )
template<int MODE>
__global__ __launch_bounds__(256) void norm_xb(const bf16* __restrict__ x,
    const float* __restrict__ w1, const float* __restrict__ w2,
    const float* __restrict__ mod, bf16* __restrict__ out, int S)
{
  const int row = blockIdx.x, tid = threadIdx.x;
  const int b = row / S;
  __shared__ float sbuf[4];
  const bf16* xr = x + (size_t)row * DIM;
  short8 vv = *(const short8*)(xr + tid*8);
  float v[8]; float ss = 0.f;
  #pragma unroll
  for (int j = 0; j < 8; j++){ v[j] = bs2f(vv[j]); ss += v[j]*v[j]; }
  ss = block_sum(ss, sbuf, tid);
  const float r = rsqrtf(ss * (1.0f/DIM) + 1e-6f);
  const float* mb = mod + (size_t)b * 6 * DIM;
  float t8[8];
  #pragma unroll
  for (int j = 0; j < 8; j++){
    int n = tid*8 + j;
    float val = v[j] * r * w1[n];
    if (MODE == 3) val = val * (1.f + mb[4*DIM + n]) + mb[3*DIM + n];
    t8[j] = val;
  }
  if (MODE == 3){
    float s2 = 0.f;
    #pragma unroll
    for (int j = 0; j < 8; j++) s2 += t8[j]*t8[j];
    s2 = block_sum(s2, sbuf, tid);
    const float r2 = rsqrtf(s2 * (1.0f/DIM) + 1e-6f);
    #pragma unroll
    for (int j = 0; j < 8; j++) t8[j] = t8[j] * r2 * w2[tid*8 + j];
  }
  short8 o;
  #pragma unroll
  for (int j = 0; j < 8; j++) o[j] = f2bs(t8[j]);
  *(short8*)(out + (size_t)row*DIM + tid*8) = o;
}

// in-place rmsnorm on bf16 rows: rows [0,M) -> xq with wq, rows [M,2M) -> xk with wk
__global__ __launch_bounds__(256) void rmsnorm2_bf16_ip(bf16* __restrict__ xq, const float* __restrict__ wq,
                                                        bf16* __restrict__ xk, const float* __restrict__ wk,
                                                        int M){
  const int row = blockIdx.x, tid = threadIdx.x;
  __shared__ float sbuf[4];
  bf16* xr; const float* w;
  if (row < M){ xr = xq + (size_t)row * DIM; w = wq; }
  else        { xr = xk + (size_t)(row - M) * DIM; w = wk; }
  short8 v = *(const short8*)(xr + tid*8);
  float f[8]; float ss = 0.f;
  #pragma unroll
  for (int j = 0; j < 8; j++){ f[j] = bs2f(v[j]); ss += f[j]*f[j]; }
  ss = block_sum(ss, sbuf, tid);
  const float r = rsqrtf(ss * (1.0f/DIM) + 1e-6f);
  short8 o;
  #pragma unroll
  for (int j = 0; j < 8; j++) o[j] = f2bs(f[j] * r * w[tid*8 + j]);
  *(short8*)(xr + tid*8) = o;
}

// ---------------- GEMM (champion): BM=128, BN=256, BK=32 ----------------
// 512 threads = 8 waves (2M x 4N), per-wave 64x64. Triple-buffered LDS,
// counted vmcnt(3), seg-XOR swizzle (0 conflicts), setprio, T1 n-major chunk.
// EPI 0: outb=bf16(v)                 1: Vt layout
// EPI 2: outb = bf16(xin[f32] + v*mod[eidx])
// EPI 3: outb = bf16(bf2f(outb) + v)
// EPI 4: gelu->outb                   5: QKV split (N=6144)
// EPI 6: KV split (N=4096)            7: outf = bf2f(out1) + v*mod[eidx]
#define GBUF 24576
template<int EPI>
__global__ __launch_bounds__(512, 2) void gemm_bf16(
    const bf16* __restrict__ A, const bf16* __restrict__ Bt,
    const float* __restrict__ bias, const float* __restrict__ xin,
    const float* __restrict__ mod, float* __restrict__ outf,
    bf16* __restrict__ outb, bf16* __restrict__ out1, bf16* __restrict__ out2,
    int M, int N, int K, int S_tok, int eidx)
{
  __shared__ __align__(16) char lds[3][GBUF];
  const int tid = threadIdx.x;
  const int w = tid >> 6, l = tid & 63;
  const int lrow = l & 15, lhi = l >> 4;
  const int wm = w >> 2, wn = w & 3;
  const int My = M >> 7;
  const int nwg = (N >> 8) * My;
  const int p = (int)blockIdx.x;
  const int fz = (p & 7) * (nwg >> 3) + (p >> 3);
  const size_t m0 = (size_t)(fz % My) * 128;
  const size_t n0 = (size_t)(fz / My) * 256;

  f32x4 acc[4][4] = {};

  auto gofs = [&](int sid){ return (size_t)(sid >> 2) * K + (size_t)(((sid & 3) ^ ((sid >> 3) & 3)) * 8); };
  const bf16* gA0 = A  + m0 * K + gofs(tid);
  const bf16* gB0 = Bt + n0 * K + gofs(tid);
  const bf16* gB1 = Bt + n0 * K + gofs(tid + 512);

  auto stage = [&](int kt, char* buf){
    const size_t ko = (size_t)kt * 32;
    gload_lds16(gA0 + ko, buf + tid * 16);
    gload_lds16(gB0 + ko, buf + 8192 + tid * 16);
    gload_lds16(gB1 + ko, buf + 8192 + (tid + 512) * 16);
  };

  const int nt = K >> 5;
  stage(0, lds[0]);
  stage(1, lds[1]);
  asm volatile("s_waitcnt vmcnt(3)" ::: "memory");
  __builtin_amdgcn_s_barrier();
  __builtin_amdgcn_sched_barrier(0);

  const int sread = (lhi ^ ((lrow >> 1) & 3)) * 16;

  int bi = 0;
  for (int t = 0; t < nt; ++t){
    const char* br = lds[bi];
    const bool st = (t + 2 < nt);
    if (st){
      int wi = bi + 2; if (wi >= 3) wi -= 3;
      stage(t + 2, lds[wi]);
    }
    short8 af[4], bf[4];
    #pragma unroll
    for (int mi = 0; mi < 4; mi++)
      af[mi] = *(const short8*)(br + (wm*64 + mi*16 + lrow)*64 + sread);
    #pragma unroll
    for (int ni = 0; ni < 4; ni++)
      bf[ni] = *(const short8*)(br + 8192 + (wn*64 + ni*16 + lrow)*64 + sread);
    __builtin_amdgcn_s_setprio(1);
    #pragma unroll
    for (int mi = 0; mi < 4; mi++)
      #pragma unroll
      for (int ni = 0; ni < 4; ni++)
        acc[mi][ni] = mfma16(af[mi], bf[ni], acc[mi][ni]);
    __builtin_amdgcn_s_setprio(0);
    if (st)               { asm volatile("s_waitcnt vmcnt(3)" ::: "memory"); }
    else if (t + 1 < nt)  { asm volatile("s_waitcnt vmcnt(0)" ::: "memory"); }
    __builtin_amdgcn_s_barrier();
    __builtin_amdgcn_sched_barrier(0);
    bi = (bi + 1 == 3) ? 0 : bi + 1;
  }

  #pragma unroll
  for (int mi = 0; mi < 4; mi++)
    #pragma unroll
    for (int ni = 0; ni < 4; ni++)
      #pragma unroll
      for (int r = 0; r < 4; r++){
        const size_t m = m0 + wm*64 + mi*16 + lhi*4 + r;
        const size_t n = n0 + wn*64 + ni*16 + lrow;
        float v = acc[mi][ni][r] + bias[n];
        if constexpr (EPI == 0) {
          outb[m * N + n] = __float2bfloat16(v);
        } else if constexpr (EPI == 1) {
          const size_t b = m / S_tok, s = m % S_tok;
          const size_t h = n >> 7, d = n & 127;
          outb[((b*HEADS + h)*HD + d) * S_tok + s] = __float2bfloat16(v);
        } else if constexpr (EPI == 2) {
          const float ev = mod[(m / S_tok) * 6 * DIM + (size_t)eidx * DIM + n];
          outb[m * N + n] = __float2bfloat16(xin[m * N + n] + v * ev);
        } else if constexpr (EPI == 3) {
          const float xv = __bfloat162float(outb[m * N + n]);
          outb[m * N + n] = __float2bfloat16(xv + v);
        } else if constexpr (EPI == 4) {
          float u = 0.7978845608028654f * (v + 0.044715f * v * v * v);
          outb[m * N + n] = __float2bfloat16(0.5f * v * (1.0f + tanhf(u)));
        } else if constexpr (EPI == 5) {   // QKV split (N = 6144)
          const size_t sg = n >> 11, col = n & 2047;
          if (sg == 0)      outb[m * DIM + col] = __float2bfloat16(v);
          else if (sg == 1) out1[m * DIM + col] = __float2bfloat16(v);
          else {
            const size_t b = m / S_tok, s = m % S_tok;
            const size_t h = col >> 7, d = col & 127;
            out2[((b*HEADS + h)*HD + d) * S_tok + s] = __float2bfloat16(v);
          }
        } else if constexpr (EPI == 6) {   // KV split (N = 4096)
          const size_t sg = n >> 11, col = n & 2047;
          if (sg == 0) out1[m * DIM + col] = __float2bfloat16(v);
          else {
            const size_t b = m / S_tok, s = m % S_tok;
            const size_t h = col >> 7, d = col & 127;
            out2[((b*HEADS + h)*HD + d) * S_tok + s] = __float2bfloat16(v);
          }
        } else {   // EPI 7: final residual, bf16 xin (out1) -> f32 out
          const float ev = mod[(m / S_tok) * 6 * DIM + (size_t)eidx * DIM + n];
          outf[m * N + n] = __bfloat162float(out1[m * N + n]) + v * ev;
        }
      }
}

// ---------------- flash attention: 32 q-rows/wave, V single-buf LDS, setprio + defer-max ----------------
__global__ __launch_bounds__(256, 2) void attn_fwd(
    const bf16* __restrict__ Q, const bf16* __restrict__ Kp, const bf16* __restrict__ Vt,
    bf16* __restrict__ O, int SQ, int SKV)
{
  const int tid = threadIdx.x, w = tid >> 6, l = tid & 63;
  const int lrow = l & 15, lhi = l >> 4;
  const int nwg = gridDim.x;
  const int p = blockIdx.x;
  const int f = (p & 7) * (nwg >> 3) + (p >> 3);
  const int nqb = SQ >> 7;
  const int xq = f % nqb;
  const int h  = (f / nqb) % HEADS;
  const int b  = f / (nqb * HEADS);
  const int q0 = xq * 128 + w * 32;

  __shared__ __align__(16) char kls[2][16384];
  __shared__ __align__(16) char vls[16384];
  __shared__ __align__(16) bf16 P[4][2][16][72];
  const float scale = 0.08838834764831845f;

  short8 qf[2][4];
  #pragma unroll
  for (int g = 0; g < 2; g++){
    const bf16* qp = Q + ((size_t)(b*SQ + q0 + g*16 + lrow))*DIM + h*HD + lhi*8;
    #pragma unroll
    for (int ds = 0; ds < 4; ds++) qf[g][ds] = *(const short8*)(qp + ds*32);
  }

  const bf16* kg = Kp + (size_t)b*SKV*DIM + h*HD;
  const bf16* vg = Vt + (size_t)(b*HEADS + h)*HD*SKV;

  f32x4 acc[2][8] = {};
  float m_run[2] = {-INFINITY, -INFINITY}, l_run[2] = {0.f, 0.f};
  const int nt = SKV >> 6;

  auto stage_k = [&](int buf, int kv0){
    char* kd = &kls[buf][0];
    #pragma unroll
    for (int i = 0; i < 4; i++){
      int sid = i*256 + tid;
      int row = sid >> 4, sg = sid & 15;
      int gsg = sg ^ (row & 7);
      gload_lds16(kg + (size_t)(kv0 + row)*DIM + gsg*8, kd + sid*16);
    }
  };
  auto stage_v = [&](int kv0){
    #pragma unroll
    for (int i = 0; i < 4; i++){
      int sid = i*256 + tid;
      int d = sid >> 3, sg = sid & 7;
      int gsg = sg ^ (d & 7);
      gload_lds16(vg + (size_t)d*SKV + kv0 + gsg*8, &vls[0] + sid*16);
    }
  };

  stage_k(0, 0);
  stage_v(0);
  asm volatile("s_waitcnt vmcnt(0)" ::: "memory");
  __builtin_amdgcn_s_barrier();

  for (int t = 0; t < nt; ++t){
    if (t > 0)      stage_v(t * 64);
    if (t + 1 < nt) stage_k((t + 1) & 1, (t + 1) * 64);
    const char* kb = &kls[t & 1][0];

    f32x4 st[2][4] = {};
    __builtin_amdgcn_s_setprio(1);
    #pragma unroll
    for (int kvf = 0; kvf < 4; kvf++){
      const int row = kvf*16 + lrow;
      const int rx = row & 7;
      #pragma unroll
      for (int ds = 0; ds < 4; ds++){
        const int seg = (ds*4 + lhi) ^ rx;
        short8 kf = *(const short8*)(kb + row*256 + seg*16);
        st[0][kvf] = mfma16(kf, qf[0][ds], st[0][kvf]);
        st[1][kvf] = mfma16(kf, qf[1][ds], st[1][kvf]);
      }
    }
    __builtin_amdgcn_s_setprio(0);

    #pragma unroll
    for (int g = 0; g < 2; g++){
      float sv[16]; float smax = -INFINITY;
      #pragma unroll
      for (int kvf = 0; kvf < 4; kvf++)
        #pragma unroll
        for (int r = 0; r < 4; r++){
          float xv = st[g][kvf][r] * scale;
          sv[kvf*4+r] = xv; smax = fmaxf(smax, xv);
        }
      smax = fmaxf(smax, __shfl_xor(smax, 16, 64));
      smax = fmaxf(smax, __shfl_xor(smax, 32, 64));
      const bool nore = __all(smax <= m_run[g] + 8.0f);
      const float mnew = nore ? m_run[g] : fmaxf(m_run[g], smax);
      float psum = 0.f;
      #pragma unroll
      for (int i = 0; i < 16; i++){ float pe = __expf(sv[i] - mnew); sv[i] = pe; psum += pe; }
      psum += __shfl_xor(psum, 16, 64); psum += __shfl_xor(psum, 32, 64);
      #pragma unroll
      for (int kvf = 0; kvf < 4; kvf++){
        short4v o;
        #pragma unroll
        for (int r = 0; r < 4; r++) o[r] = f2bs(sv[kvf*4+r]);
        *(short4v*)&P[w][g][lrow][kvf*16 + lhi*4] = o;
      }
      if (nore){
        l_run[g] += psum;
      } else {
        const float corr = __expf(m_run[g] - mnew);
        l_run[g] = l_run[g] * corr + psum;
        m_run[g] = mnew;
        float cr[4];
        #pragma unroll
        for (int r = 0; r < 4; r++) cr[r] = __shfl(corr, lhi*4 + r, 64);
        #pragma unroll
        for (int df = 0; df < 8; df++){
          acc[g][df][0] *= cr[0]; acc[g][df][1] *= cr[1];
          acc[g][df][2] *= cr[2]; acc[g][df][3] *= cr[3];
        }
      }
    }

    if (t + 1 < nt) { asm volatile("s_waitcnt vmcnt(4)" ::: "memory"); }
    else            { asm volatile("s_waitcnt vmcnt(0)" ::: "memory"); }
    __builtin_amdgcn_s_barrier();
    asm volatile("s_waitcnt lgkmcnt(0)" ::: "memory");
    __builtin_amdgcn_sched_barrier(0);

    short8 pf[2][2];
    #pragma unroll
    for (int g = 0; g < 2; g++){
      pf[g][0] = *(const short8*)&P[w][g][lrow][lhi*8];
      pf[g][1] = *(const short8*)&P[w][g][lrow][32 + lhi*8];
    }
    __builtin_amdgcn_s_setprio(1);
    #pragma unroll
    for (int df = 0; df < 8; df++){
      const int d = df*16 + lrow;
      const int dx = d & 7;
      short8 vf0 = *(const short8*)(&vls[0] + d*128 + ((lhi)     ^ dx)*16);
      short8 vf1 = *(const short8*)(&vls[0] + d*128 + ((lhi + 4) ^ dx)*16);
      acc[0][df] = mfma16(pf[0][0], vf0, acc[0][df]);
      acc[0][df] = mfma16(pf[0][1], vf1, acc[0][df]);
      acc[1][df] = mfma16(pf[1][0], vf0, acc[1][df]);
      acc[1][df] = mfma16(pf[1][1], vf1, acc[1][df]);
    }
    __builtin_amdgcn_s_setprio(0);
    if (t + 1 < nt) { asm volatile("s_waitcnt vmcnt(0)" ::: "memory"); }
    __builtin_amdgcn_s_barrier();
  }

  #pragma unroll
  for (int g = 0; g < 2; g++){
    const float linv = 1.0f / l_run[g];
    float li[4];
    #pragma unroll
    for (int r = 0; r < 4; r++) li[r] = __shfl(linv, lhi*4 + r, 64);
    #pragma unroll
    for (int df = 0; df < 8; df++)
      #pragma unroll
      for (int r = 0; r < 4; r++){
        const size_t q = q0 + g*16 + lhi*4 + r;
        O[((size_t)(b*SQ + q))*DIM + h*HD + df*16 + lrow] = __float2bfloat16(acc[g][df][r] * li[r]);
      }
  }
}

// ---------------- host ----------------

extern "C" void kernel_launch(void* const* d_in, const int* in_sizes, int n_in,
                              void* d_out, int out_size, void* d_ws, size_t ws_size,
                              hipStream_t stream)
{
  const float* x    = (const float*)d_in[0];
  const float* e    = (const float*)d_in[1];
  const float* ctx  = (const float*)d_in[2];
  const float* modw = (const float*)d_in[3];
  const float* n1w  = (const float*)d_in[4];
  const float* n2w  = (const float*)d_in[5];
  const float* n3w  = (const float*)d_in[6];
  const float* nqw  = (const float*)d_in[7];
  const float* nkw  = (const float*)d_in[8];
  const float* fnw  = (const float*)d_in[9];
  const float* saqw = (const float*)d_in[10]; const float* saqb = (const float*)d_in[11];
  const float* sakw = (const float*)d_in[12]; const float* sakb = (const float*)d_in[13];
  const float* savw = (const float*)d_in[14]; const float* savb = (const float*)d_in[15];
  const float* saow = (const float*)d_in[16]; const float* saob = (const float*)d_in[17];
  const float* caqw = (const float*)d_in[18]; const float* caqb = (const float*)d_in[19];
  const float* cakw = (const float*)d_in[20]; const float* cakb = (const float*)d_in[21];
  const float* cavw = (const float*)d_in[22]; const float* cavb = (const float*)d_in[23];
  const float* caow = (const float*)d_in[24]; const float* caob = (const float*)d_in[25];
  const float* fw1  = (const float*)d_in[26]; const float* fb1  = (const float*)d_in[27];
  const float* fw2  = (const float*)d_in[28]; const float* fb2  = (const float*)d_in[29];
  float* out = (float*)d_out;
  (void)in_sizes; (void)n_in; (void)out_size; (void)ws_size;

  char* ws = (char*)d_ws;
  size_t off = 0;
  auto alloc = [&](size_t bytes) -> void* {
    void* p = ws + off; off = (off + bytes + 255) & ~(size_t)255; return p;
  };
  bf16*  wt   = (bf16*)alloc((size_t)FFND * DIM * 2);
  float* mod  = (float*)alloc((size_t)BATCH * 6 * DIM * 4);
  float* bcat = (float*)alloc((size_t)3 * DIM * 4);
  float* bcat2= (float*)alloc((size_t)2 * DIM * 4);
  bf16*  ctxb = (bf16*)alloc((size_t)BATCH * CLEN * DIM * 2);
  bf16*  hbuf = (bf16*)alloc((size_t)BATCH * SEQ * DIM * 2);
  bf16*  qbuf = (bf16*)alloc((size_t)BATCH * SEQ * DIM * 2);
  bf16*  kbuf = (bf16*)alloc((size_t)BATCH * SEQ * DIM * 2);
  bf16*  vtb  = (bf16*)alloc((size_t)BATCH * SEQ * DIM * 2);
  bf16*  aout = (bf16*)alloc((size_t)BATCH * SEQ * DIM * 2);
  bf16*  xcurb= (bf16*)alloc((size_t)BATCH * SEQ * DIM * 2);
  bf16*  hf   = (bf16*)alloc((size_t)BATCH * SEQ * FFND * 2);

  const int M = BATCH * SEQ;     // 4096
  const int Mc = BATCH * CLEN;   // 1024

  prologue_k<<<dim3(1160), dim3(256), 0, stream>>>(modw, e, mod, ctx, ctxb,
                                                   saqb, sakb, savb, cakb, cavb, bcat, bcat2);

  // --- self attention: fused QKV (N=6144) ---
  norm_x<<<dim3(M), dim3(256), 0, stream>>>(x, n1w, mod, hbuf, SEQ);

  transpose_w3<<<dim3(DIM/64, DIM/64, 3), dim3(256), 0, stream>>>(saqw, sakw, savw, wt, DIM, DIM);
  gemm_bf16<5><<<dim3((3*DIM/256)*(M/128)), dim3(512), 0, stream>>>(hbuf, wt, bcat, nullptr, nullptr, nullptr, qbuf, kbuf, vtb, M, 3*DIM, DIM, SEQ, 0);
  rmsnorm2_bf16_ip<<<dim3(2*M), dim3(256), 0, stream>>>(qbuf, nqw, kbuf, nkw, M);

  attn_fwd<<<dim3((SEQ/128)*HEADS*BATCH), dim3(256), 0, stream>>>(qbuf, kbuf, vtb, aout, SEQ, SEQ);

  transpose_w<<<dim3(DIM/64, DIM/64), dim3(256), 0, stream>>>(saow, wt, DIM, DIM);
  gemm_bf16<2><<<dim3((DIM/256)*(M/128)), dim3(512), 0, stream>>>(aout, wt, saob, x, mod, nullptr, xcurb, nullptr, nullptr, M, DIM, DIM, SEQ, 2);

  // --- cross attention: q gemm + fused KV gemm (N=4096) ---
  norm_xb<2><<<dim3(M), dim3(256), 0, stream>>>(xcurb, n2w, nullptr, mod, hbuf, SEQ);

  transpose_w3<<<dim3(DIM/64, DIM/64, 3), dim3(256), 0, stream>>>(caqw, cakw, cavw, wt, DIM, DIM);
  gemm_bf16<0><<<dim3((DIM/256)*(M/128)), dim3(512), 0, stream>>>(hbuf, wt, caqb, nullptr, nullptr, nullptr, qbuf, nullptr, nullptr, M, DIM, DIM, SEQ, 0);
  gemm_bf16<6><<<dim3((2*DIM/256)*(Mc/128)), dim3(512), 0, stream>>>(ctxb, wt + (size_t)DIM*DIM, bcat2, nullptr, nullptr, nullptr, nullptr, kbuf, vtb, Mc, 2*DIM, DIM, CLEN, 0);

  attn_fwd<<<dim3((SEQ/128)*HEADS*BATCH), dim3(256), 0, stream>>>(qbuf, kbuf, vtb, aout, SEQ, CLEN);

  transpose_w<<<dim3(DIM/64, DIM/64), dim3(256), 0, stream>>>(caow, wt, DIM, DIM);
  gemm_bf16<3><<<dim3((DIM/256)*(M/128)), dim3(512), 0, stream>>>(aout, wt, caob, nullptr, nullptr, nullptr, xcurb, nullptr, nullptr, M, DIM, DIM, SEQ, 0);

  // --- FFN ---
  norm_xb<3><<<dim3(M), dim3(256), 0, stream>>>(xcurb, n3w, fnw, mod, hbuf, SEQ);

  transpose_w<<<dim3(FFND/64, DIM/64), dim3(256), 0, stream>>>(fw1, wt, DIM, FFND);
  gemm_bf16<4><<<dim3((FFND/256)*(M/128)), dim3(512), 0, stream>>>(hbuf, wt, fb1, nullptr, nullptr, nullptr, hf, nullptr, nullptr, M, FFND, DIM, SEQ, 0);

  transpose_w<<<dim3(DIM/64, FFND/64), dim3(256), 0, stream>>>(fw2, wt, FFND, DIM);
  gemm_bf16<7><<<dim3((DIM/256)*(M/128)), dim3(512), 0, stream>>>(hf, wt, fb2, nullptr, mod, out, nullptr, xcurb, nullptr, M, DIM, FFND, SEQ, 5);
}